// Round 1
// baseline (3835.583 us; speedup 1.0000x reference)
//
#include <hip/hip_runtime.h>

// BiLSTM-CRF forward. B=64, L=1024, E=256, H=128 (per dir), C=5, V=32000.
// Pipeline: conv weights -> embed gather -> GEMM1 (x@Wih1) -> persistent LSTM1
// -> attention (softmax + rank-1 proj) -> GEMM2 (y1@Wih2[:, :256]) -> add attn
// -> persistent LSTM2 -> feats (@Wout) -> CRF forward alg.

typedef unsigned short u16;
typedef __bf16 v8bf __attribute__((ext_vector_type(8)));
typedef float  v4f  __attribute__((ext_vector_type(4)));
typedef unsigned short u16x8 __attribute__((ext_vector_type(8)));
typedef unsigned short u16x4 __attribute__((ext_vector_type(4)));

__device__ __forceinline__ float b2f(u16 b){
  return __builtin_bit_cast(float, ((unsigned)b) << 16);
}
__device__ __forceinline__ u16 f2b(float x){           // RNE f32->bf16
  unsigned u = __builtin_bit_cast(unsigned, x);
  unsigned r = (u + 0x7FFFu + ((u >> 16) & 1u)) >> 16;
  return (u16)r;
}
__device__ __forceinline__ float sigm(float x){
  return __builtin_amdgcn_rcpf(1.0f + __expf(-x));
}
__device__ __forceinline__ float tanh_(float x){
  float xx = fminf(fmaxf(x, -15.0f), 15.0f);
  float e  = __expf(-2.0f * xx);
  return (1.0f - e) * __builtin_amdgcn_rcpf(1.0f + e);
}

// ---------------- weight prep: concat + fp32->bf16 ----------------
__global__ __launch_bounds__(256) void conv_weights(
    const float* __restrict__ Wih1f, const float* __restrict__ Wih1b,
    const float* __restrict__ bih1f, const float* __restrict__ bhh1f,
    const float* __restrict__ bih1b, const float* __restrict__ bhh1b,
    const float* __restrict__ Wih2f, const float* __restrict__ Wih2b,
    const float* __restrict__ bih2f, const float* __restrict__ bhh2f,
    const float* __restrict__ bih2b, const float* __restrict__ bhh2b,
    u16* __restrict__ W1cat, u16* __restrict__ WAcat,
    float* __restrict__ b1cat, float* __restrict__ b2cat)
{
  int gid = blockIdx.x * 256 + threadIdx.x;   // 1024*256 = 262144
  int j = gid >> 8, e = gid & 255;
  float w1 = (j < 512) ? Wih1f[j*256 + e] : Wih1b[(j-512)*256 + e];
  float wa = (j < 512) ? Wih2f[j*512 + e] : Wih2b[(j-512)*512 + e];  // cols 0..255
  W1cat[gid] = f2b(w1);
  WAcat[gid] = f2b(wa);
  if (e == 0){
    b1cat[j] = (j < 512) ? (bih1f[j] + bhh1f[j]) : (bih1b[j-512] + bhh1b[j-512]);
    b2cat[j] = (j < 512) ? (bih2f[j] + bhh2f[j]) : (bih2b[j-512] + bhh2b[j-512]);
  }
}

// ---------------- embedding gather (flat order == reshape(L,B,E)) ----------------
__global__ __launch_bounds__(256) void embed_gather(
    const int* __restrict__ sent, const float* __restrict__ emb, u16* __restrict__ X)
{
  int w = threadIdx.x >> 6, lane = threadIdx.x & 63;
  long i = (long)blockIdx.x * 4 + w;          // row of X, 0..65535
  int idx = sent[i];
  const float4* src = (const float4*)(emb + (long)idx * 256);
  float4 v = src[lane];
  u16x4 o; o[0] = f2b(v.x); o[1] = f2b(v.y); o[2] = f2b(v.z); o[3] = f2b(v.w);
  *(u16x4*)(X + i*256 + lane*4) = o;
}

// ---------------- bf16 MFMA GEMM, A[MxK] row-major, B[NxK] row-major (B^T), +bias, bf16 out ----
__global__ __launch_bounds__(256) void gemm_bt(
    const u16* __restrict__ A, const u16* __restrict__ Bm,
    const float* __restrict__ bias, u16* __restrict__ C,
    int M, int N, int K)
{
  __shared__ __align__(16) u16 As[128*64];
  __shared__ __align__(16) u16 Bs[128*64];
  int tid = threadIdx.x;
  int w = tid >> 6, lane = tid & 63;
  int lq = lane & 15, quad = lane >> 4;
  int wm = w & 1, wn = w >> 1;
  long m0 = (long)blockIdx.x * 128, n0 = (long)blockIdx.y * 128;
  v4f acc[4][4];
  v4f zero = {0.f, 0.f, 0.f, 0.f};
#pragma unroll
  for (int i=0;i<4;i++)
#pragma unroll
    for (int j=0;j<4;j++) acc[i][j] = zero;

  for (int k0 = 0; k0 < K; k0 += 64){
#pragma unroll
    for (int c = 0; c < 4; c++){
      int lin = c*256 + tid;
      int row = lin >> 3, chunk = lin & 7;            // 128 rows x 8 chunks(16B)
      u16x8 av = *(const u16x8*)(A + (m0+row)*K + k0 + chunk*8);
      u16x8 bv = *(const u16x8*)(Bm + (n0+row)*K + k0 + chunk*8);
      int sw = chunk ^ (row & 7);                     // XOR swizzle vs bank conflicts
      *(u16x8*)(As + row*64 + sw*8) = av;
      *(u16x8*)(Bs + row*64 + sw*8) = bv;
    }
    __syncthreads();
#pragma unroll
    for (int s = 0; s < 2; s++){
      v8bf af[4], bf_[4];
#pragma unroll
      for (int i=0;i<4;i++){
        int row = wm*64 + i*16 + lq;
        int ch  = (s*4 + quad) ^ (row & 7);
        af[i] = __builtin_bit_cast(v8bf, *(const u16x8*)(As + row*64 + ch*8));
      }
#pragma unroll
      for (int j=0;j<4;j++){
        int row = wn*64 + j*16 + lq;
        int ch  = (s*4 + quad) ^ (row & 7);
        bf_[j] = __builtin_bit_cast(v8bf, *(const u16x8*)(Bs + row*64 + ch*8));
      }
#pragma unroll
      for (int i=0;i<4;i++)
#pragma unroll
        for (int j=0;j<4;j++)
          acc[i][j] = __builtin_amdgcn_mfma_f32_16x16x32_bf16(af[i], bf_[j], acc[i][j], 0, 0, 0);
    }
    __syncthreads();
  }
#pragma unroll
  for (int j=0;j<4;j++){
    long col = n0 + wn*64 + j*16 + lq;
    float bv = bias[col];
#pragma unroll
    for (int i=0;i<4;i++){
      long rbase = m0 + wm*64 + i*16 + quad*4;
#pragma unroll
      for (int r=0;r<4;r++)
        C[(rbase + r)*N + col] = f2b(acc[i][j][r] + bv);
    }
  }
}

// ---------------- persistent BiLSTM layer: 8 WGs (2 dirs x 4 batch groups of 16) ----------------
// G: [L*64, 1024] bf16 (dir d at cols d*512, gate order i,f,g,o x128)
// Y: [L, 64, 256] bf16 (dir d at cols d*128). catOut: [64,256] fp32 final cells (or null).
__global__ __launch_bounds__(512) void lstm_layer(
    const u16* __restrict__ G, const float* __restrict__ WhhF, const float* __restrict__ WhhB,
    const float* __restrict__ h0, const float* __restrict__ c0,
    u16* __restrict__ Y, float* __restrict__ catOut)
{
  int blk = blockIdx.x;
  int dir = blk >> 2, bg = blk & 3, b0 = bg * 16;
  int tid = threadIdx.x, w = tid >> 6, lane = tid & 63;
  int quad = lane >> 4, lq = lane & 15;
  int hidx = w*16 + lq;                       // 0..127: this lane's hidden unit
  const float* Whh = dir ? WhhB : WhhF;

  __shared__ __align__(16) u16 hbuf[2][2048]; // h in A-frag layout, double buffered

  // Whh as B-fragments in registers: wave w owns ntiles {w+8t}, t = gate index.
  v8bf Bfrag[4][4];                           // [gate t][kstep]
#pragma unroll
  for (int t=0;t<4;t++)
#pragma unroll
    for (int ks=0;ks<4;ks++){
      int n  = (w + 8*t)*16 + lq;             // 0..511
      int kk = ks*32 + quad*8;
      u16x8 tmp;
#pragma unroll
      for (int jj=0;jj<8;jj++) tmp[jj] = f2b(Whh[n*128 + kk + jj]);
      Bfrag[t][ks] = __builtin_bit_cast(v8bf, tmp);
    }

  // per-lane cell state: batches m = quad*4+r at hidden unit hidx
  float cc[4];
  int kst = hidx >> 5, rr = hidx & 31, q2 = rr >> 3, jj0 = rr & 7;
  int hoff = (kst*4 + q2)*128 + jj0;          // + m*8 -> element in frag layout
#pragma unroll
  for (int r=0;r<4;r++){
    int m = quad*4 + r;
    cc[r] = c0[dir*8192 + (b0+m)*128 + hidx];
    hbuf[0][hoff + m*8] = f2b(h0[dir*8192 + (b0+m)*128 + hidx]);
  }

#define LIDX(it) (dir ? (1023 - (it)) : (it))
  u16 gva[16], gvb[16];                       // depth-2 G prefetch
  {
    long l0 = LIDX(0), l1 = LIDX(1);
#pragma unroll
    for (int t=0;t<4;t++)
#pragma unroll
      for (int r=0;r<4;r++){
        gva[t*4+r] = G[(l0*64 + b0 + quad*4 + r)*1024 + dir*512 + t*128 + hidx];
        gvb[t*4+r] = G[(l1*64 + b0 + quad*4 + r)*1024 + dir*512 + t*128 + hidx];
      }
  }
  int p = 0;
  __syncthreads();

  for (int it = 0; it < 1024; ++it){
    long l = LIDX(it);
    float gcur[16];
#pragma unroll
    for (int z=0;z<16;z++){ gcur[z] = b2f(gva[z]); gva[z] = gvb[z]; }
    if (it + 2 < 1024){
      long l2 = LIDX(it+2);
#pragma unroll
      for (int t=0;t<4;t++)
#pragma unroll
        for (int r=0;r<4;r++)
          gvb[t*4+r] = G[(l2*64 + b0 + quad*4 + r)*1024 + dir*512 + t*128 + hidx];
    }
    v8bf af[4];
#pragma unroll
    for (int ks=0;ks<4;ks++)
      af[ks] = __builtin_bit_cast(v8bf, *(const u16x8*)(&hbuf[p][(ks*64 + lane)*8]));
    v4f acc[4];
#pragma unroll
    for (int t=0;t<4;t++){
      v4f tv = {gcur[t*4+0], gcur[t*4+1], gcur[t*4+2], gcur[t*4+3]};
      acc[t] = tv;
    }
#pragma unroll
    for (int ks=0;ks<4;ks++)
#pragma unroll
      for (int t=0;t<4;t++)
        acc[t] = __builtin_amdgcn_mfma_f32_16x16x32_bf16(af[ks], Bfrag[t][ks], acc[t], 0, 0, 0);

    int pn = p ^ 1;
#pragma unroll
    for (int r=0;r<4;r++){
      int m = quad*4 + r;
      float ig = sigm(acc[0][r]);
      float fg = sigm(acc[1][r]);
      float gg = tanh_(acc[2][r]);
      float og = sigm(acc[3][r]);
      float c2 = fg*cc[r] + ig*gg;
      cc[r] = c2;
      float hv = og * tanh_(c2);
      u16 hb = f2b(hv);
      hbuf[pn][hoff + m*8] = hb;
      Y[(l*64 + b0 + m)*256 + dir*128 + hidx] = hb;
    }
    p = pn;
    __syncthreads();
  }
  if (catOut){
#pragma unroll
    for (int r=0;r<4;r++){
      int m = quad*4 + r;
      catOut[(b0+m)*256 + dir*128 + hidx] = cc[r];
    }
  }
#undef LIDX
}

// ---------------- attention: e = fbout . catc, softmax over L, proj = catc @ Wih2[:,256:].T ----
__global__ __launch_bounds__(256) void attn_kernel(
    const u16* __restrict__ y1, const float* __restrict__ catc,
    const float* __restrict__ Wih2f, const float* __restrict__ Wih2b,
    float* __restrict__ s_buf, float* __restrict__ proj)
{
  int b = blockIdx.x, t = threadIdx.x;
  __shared__ float catv[256];
  __shared__ float ev[1024];
  __shared__ float red[256];
  catv[t] = catc[b*256 + t];
  __syncthreads();
  float evl[4];
#pragma unroll
  for (int r2=0;r2<4;r2++){
    int l = t + r2*256;
    const u16x8* row = (const u16x8*)(y1 + ((long)l*64 + b)*256);
    float acc = 0.f;
    for (int f8=0; f8<32; f8++){
      u16x8 v = row[f8];
#pragma unroll
      for (int k=0;k<8;k++) acc += b2f(v[k]) * catv[f8*8+k];
    }
    ev[l] = acc; evl[r2] = acc;
  }
  float mx = fmaxf(fmaxf(evl[0],evl[1]), fmaxf(evl[2],evl[3]));
  red[t] = mx;
  __syncthreads();
  for (int s=128; s>0; s>>=1){ if (t < s) red[t] = fmaxf(red[t], red[t+s]); __syncthreads(); }
  float m = red[0];
  __syncthreads();
  float sum = 0.f;
#pragma unroll
  for (int r2=0;r2<4;r2++){
    int l = t + r2*256;
    float e = __expf(ev[l] - m);
    ev[l] = e; sum += e;
  }
  red[t] = sum;
  __syncthreads();
  for (int s=128; s>0; s>>=1){ if (t < s) red[t] += red[t+s]; __syncthreads(); }
  float rz = __builtin_amdgcn_rcpf(red[0]);
#pragma unroll
  for (int r2=0;r2<4;r2++){
    int l = t + r2*256;
    s_buf[b*1024 + l] = ev[l] * rz;
  }
#pragma unroll
  for (int r2=0;r2<4;r2++){
    int j = t + r2*256;
    const float* wr = (j < 512) ? (Wih2f + (long)j*512 + 256)
                                : (Wih2b + (long)(j-512)*512 + 256);
    const float4* w4 = (const float4*)wr;
    float acc = 0.f;
#pragma unroll 8
    for (int f4=0; f4<64; f4++){
      float4 v = w4[f4];
      acc += v.x*catv[f4*4+0] + v.y*catv[f4*4+1] + v.z*catv[f4*4+2] + v.w*catv[f4*4+3];
    }
    proj[b*1024 + j] = acc;
  }
}

// ---------------- G2 += 64 * s[b,l] * proj[b,j] ----------------
__global__ __launch_bounds__(256) void addattn(u16* __restrict__ G2,
    const float* __restrict__ s_buf, const float* __restrict__ proj)
{
  long gid = (long)blockIdx.x * 256 + threadIdx.x;  // 65536*128
  long i = gid >> 7;
  int jc = (int)(gid & 127) * 8;
  int b = (int)(i & 63); long l = i >> 6;
  float f = 64.0f * s_buf[b*1024 + l];
  const float* pr = proj + b*1024 + jc;
  u16x8* p = (u16x8*)(G2 + i*1024 + jc);
  u16x8 v = *p;
#pragma unroll
  for (int k=0;k<8;k++) v[k] = f2b(b2f(v[k]) + f*pr[k]);
  *p = v;
}

// ---------------- feats = out2 @ Wout.T + bout (flat-order reshape => row i maps 1:1) ----------
__global__ __launch_bounds__(256) void featk(const u16* __restrict__ y2,
    const float* __restrict__ Wout, const float* __restrict__ bout, float* __restrict__ feats)
{
  __shared__ float wlds[1280];
  int t = threadIdx.x;
  for (int k=t;k<1280;k+=256) wlds[k] = Wout[k];
  __syncthreads();
  long i = (long)blockIdx.x*256 + t;
  const u16x8* row = (const u16x8*)(y2 + i*256);
  float acc[5] = {0.f,0.f,0.f,0.f,0.f};
  for (int f8=0; f8<32; f8++){
    u16x8 v = row[f8];
#pragma unroll
    for (int k=0;k<8;k++){
      float x = b2f(v[k]);
      int f = f8*8 + k;
#pragma unroll
      for (int c=0;c<5;c++) acc[c] += x * wlds[c*256 + f];
    }
  }
#pragma unroll
  for (int c=0;c<5;c++) feats[i*5 + c] = acc[c] + bout[c];
}

// ---------------- CRF forward algorithm: 1 wave, thread b owns state row ----------------
__global__ void crf_kernel(const float* __restrict__ feats, const float* __restrict__ masks,
                           const float* __restrict__ trans, float* __restrict__ out)
{
  int b = threadIdx.x;  // 64
  float etr[5][5], tr4[5];
#pragma unroll
  for (int c=0;c<5;c++)
#pragma unroll
    for (int cp=0;cp<5;cp++) etr[c][cp] = __expf(trans[c*5+cp]);
#pragma unroll
  for (int cp=0;cp<5;cp++) tr4[cp] = trans[4*5+cp];   // STOP row
  float sc[5];
#pragma unroll
  for (int c=0;c<5;c++) sc[c] = (c==3) ? 0.f : -10000.f;  // START=3
  float ftn[5], mtn;
#pragma unroll
  for (int c=0;c<5;c++) ftn[c] = feats[(long)b*1024*5 + c];
  mtn = masks[b*1024];
  for (int l=0;l<1024;l++){
    float ft[5]; float mt = mtn;
#pragma unroll
    for (int c=0;c<5;c++) ft[c] = ftn[c];
    if (l < 1023){
      const float* fp = feats + ((long)b*1024 + l + 1)*5;
#pragma unroll
      for (int c=0;c<5;c++) ftn[c] = fp[c];
      mtn = masks[b*1024 + l + 1];
    }
    float m = sc[0];
#pragma unroll
    for (int c=1;c<5;c++) m = fmaxf(m, sc[c]);
    float E[5];
#pragma unroll
    for (int cp=0;cp<5;cp++) E[cp] = __expf(sc[cp] - m);
    float st[5];
#pragma unroll
    for (int c=0;c<5;c++){
      float S = E[0]*etr[c][0] + E[1]*etr[c][1] + E[2]*etr[c][2]
              + E[3]*etr[c][3] + E[4]*etr[c][4];
      st[c] = ft[c] + m + __logf(S + 1e-30f);   // clamp keeps START row finite (no 0*inf NaN)
    }
#pragma unroll
    for (int c=0;c<5;c++) sc[c] = st[c]*mt + sc[c]*(1.f - mt);
  }
  float m2 = sc[0] + tr4[0];
#pragma unroll
  for (int cp=1;cp<5;cp++) m2 = fmaxf(m2, sc[cp] + tr4[cp]);
  float S2 = 0.f;
#pragma unroll
  for (int cp=0;cp<5;cp++) S2 += __expf(sc[cp] + tr4[cp] - m2);
  out[b] = m2 + __logf(S2);
}

// ---------------- launcher ----------------
extern "C" void kernel_launch(void* const* d_in, const int* in_sizes, int n_in,
                              void* d_out, int out_size, void* d_ws, size_t ws_size,
                              hipStream_t stream)
{
  const int*   sent  = (const int*)  d_in[0];
  const float* masks = (const float*)d_in[1];
  const float* emb   = (const float*)d_in[2];
  const float* Wih1f = (const float*)d_in[3];
  const float* Whh1f = (const float*)d_in[4];
  const float* bih1f = (const float*)d_in[5];
  const float* bhh1f = (const float*)d_in[6];
  const float* Wih1b = (const float*)d_in[7];
  const float* Whh1b = (const float*)d_in[8];
  const float* bih1b = (const float*)d_in[9];
  const float* bhh1b = (const float*)d_in[10];
  const float* Wih2f = (const float*)d_in[11];
  const float* Whh2f = (const float*)d_in[12];
  const float* bih2f = (const float*)d_in[13];
  const float* bhh2f = (const float*)d_in[14];
  const float* Wih2b = (const float*)d_in[15];
  const float* Whh2b = (const float*)d_in[16];
  const float* bih2b = (const float*)d_in[17];
  const float* bhh2b = (const float*)d_in[18];
  const float* Wout  = (const float*)d_in[19];
  const float* bout  = (const float*)d_in[20];
  const float* trans = (const float*)d_in[21];
  const float* h0    = (const float*)d_in[22];
  const float* c0    = (const float*)d_in[23];
  const float* h02   = (const float*)d_in[24];
  const float* c02   = (const float*)d_in[25];
  float* out = (float*)d_out;

  // workspace layout (aliased: X/y1/y2 share, G1/G2 share). Total ~170.7 MB.
  char* ws = (char*)d_ws;
  u16*   Ybuf  = (u16*)(ws + 0);              // 33,554,432 B: X, then y1, then y2
  u16*   Gbuf  = (u16*)(ws + 33554432);       // 134,217,728 B: G1, then G2
  u16*   W1cat = (u16*)(ws + 167772160);      // 524,288 B
  u16*   WAcat = (u16*)(ws + 168296448);      // 524,288 B
  float* b1cat = (float*)(ws + 168820736);    // 4,096 B
  float* b2cat = (float*)(ws + 168824832);    // 4,096 B
  float* catcb = (float*)(ws + 168828928);    // 65,536 B
  float* sbuf  = (float*)(ws + 168894464);    // 262,144 B
  float* projb = (float*)(ws + 169156608);    // 262,144 B
  float* featb = (float*)(ws + 169418752);    // 1,310,720 B

  conv_weights<<<1024, 256, 0, stream>>>(Wih1f, Wih1b, bih1f, bhh1f, bih1b, bhh1b,
                                         Wih2f, Wih2b, bih2f, bhh2f, bih2b, bhh2b,
                                         W1cat, WAcat, b1cat, b2cat);
  embed_gather<<<16384, 256, 0, stream>>>(sent, emb, Ybuf);
  gemm_bt<<<dim3(512, 8), 256, 0, stream>>>(Ybuf, W1cat, b1cat, Gbuf, 65536, 1024, 256);
  lstm_layer<<<8, 512, 0, stream>>>(Gbuf, Whh1f, Whh1b, h0, c0, Ybuf, catcb);
  attn_kernel<<<64, 256, 0, stream>>>(Ybuf, catcb, Wih2f, Wih2b, sbuf, projb);
  gemm_bt<<<dim3(512, 8), 256, 0, stream>>>(Ybuf, WAcat, b2cat, Gbuf, 65536, 1024, 256);
  addattn<<<32768, 256, 0, stream>>>(Gbuf, sbuf, projb);
  lstm_layer<<<8, 512, 0, stream>>>(Gbuf, Whh2f, Whh2b, h02, c02, Ybuf, nullptr);
  featk<<<256, 256, 0, stream>>>(Ybuf, Wout, bout, featb);
  crf_kernel<<<1, 64, 0, stream>>>(featb, masks, trans, out);
}

// Round 2
// 3036.023 us; speedup vs baseline: 1.2634x; 1.2634x over previous
//
#include <hip/hip_runtime.h>
#include <hip/hip_bf16.h>

// BiLSTM-CRF forward. B=64, L=1024, E=256, H=128 (per dir), C=5, V=32000.
// R1: GEMM writes gate tensor in LSTM-thread-ordered layout G'[grp][l][tid][16]
// (2x dwordx4 per step instead of 16 scalar loads); attention folded into LSTM2
// (rank-1: 64*s[l,b]*proj[b,j], proj in regs); lean activations; addattn killed.

typedef unsigned short u16;
typedef __bf16 v8bf __attribute__((ext_vector_type(8)));
typedef float  v4f  __attribute__((ext_vector_type(4)));
typedef unsigned short u16x8 __attribute__((ext_vector_type(8)));
typedef unsigned short u16x4 __attribute__((ext_vector_type(4)));

__device__ __forceinline__ float b2f(u16 b){
  return __builtin_bit_cast(float, ((unsigned)b) << 16);
}
__device__ __forceinline__ u16 f2b(float x){           // RNE f32->bf16
  unsigned u = __builtin_bit_cast(unsigned, x);
  unsigned r = (u + 0x7FFFu + ((u >> 16) & 1u)) >> 16;
  return (u16)r;
}
__device__ __forceinline__ float sg(float x){          // sigmoid, 4 ops
  return __builtin_amdgcn_rcpf(1.0f + __expf(-x));
}
__device__ __forceinline__ float th(float x){          // tanh = 2*sigm(2x)-1, 5 ops
  return fmaf(2.0f, __builtin_amdgcn_rcpf(1.0f + __expf(-2.0f*x)), -1.0f);
}

// ---------------- weight prep: concat + fp32->bf16 ----------------
__global__ __launch_bounds__(256) void conv_weights(
    const float* __restrict__ Wih1f, const float* __restrict__ Wih1b,
    const float* __restrict__ bih1f, const float* __restrict__ bhh1f,
    const float* __restrict__ bih1b, const float* __restrict__ bhh1b,
    const float* __restrict__ Wih2f, const float* __restrict__ Wih2b,
    const float* __restrict__ bih2f, const float* __restrict__ bhh2f,
    const float* __restrict__ bih2b, const float* __restrict__ bhh2b,
    u16* __restrict__ W1cat, u16* __restrict__ WAcat,
    float* __restrict__ b1cat, float* __restrict__ b2cat)
{
  int gid = blockIdx.x * 256 + threadIdx.x;   // 1024*256 = 262144
  int j = gid >> 8, e = gid & 255;
  float w1 = (j < 512) ? Wih1f[j*256 + e] : Wih1b[(j-512)*256 + e];
  float wa = (j < 512) ? Wih2f[j*512 + e] : Wih2b[(j-512)*512 + e];  // cols 0..255
  W1cat[gid] = f2b(w1);
  WAcat[gid] = f2b(wa);
  if (e == 0){
    b1cat[j] = (j < 512) ? (bih1f[j] + bhh1f[j]) : (bih1b[j-512] + bhh1b[j-512]);
    b2cat[j] = (j < 512) ? (bih2f[j] + bhh2f[j]) : (bih2b[j-512] + bhh2b[j-512]);
  }
}

// ---------------- embedding gather (flat order == reshape(L,B,E)) ----------------
__global__ __launch_bounds__(256) void embed_gather(
    const int* __restrict__ sent, const float* __restrict__ emb, u16* __restrict__ X)
{
  int w = threadIdx.x >> 6, lane = threadIdx.x & 63;
  long i = (long)blockIdx.x * 4 + w;          // row of X, 0..65535
  int idx = sent[i];
  const float4* src = (const float4*)(emb + (long)idx * 256);
  float4 v = src[lane];
  u16x4 o; o[0] = f2b(v.x); o[1] = f2b(v.y); o[2] = f2b(v.z); o[3] = f2b(v.w);
  *(u16x4*)(X + i*256 + lane*4) = o;
}

// ---- bf16 MFMA GEMM, A[MxK] rm, B[NxK] rm, +bias; writes G'[grp][l][tid][16] ----
// grp = dir*4+bg; l = i>>6; b = i&63; j -> dir=j>>9, t=(j>>7)&3, hx=j&127
// tid = (hx>>4)*64 + ((b&15)>>2)*16 + (hx&15); z = t*4 + (b&3)
__global__ __launch_bounds__(256) void gemm_bt(
    const u16* __restrict__ A, const u16* __restrict__ Bm,
    const float* __restrict__ bias, u16* __restrict__ Gp,
    int M, int N, int K)
{
  __shared__ __align__(16) u16 As[128*64];
  __shared__ __align__(16) u16 Bs[128*64];
  int tid = threadIdx.x;
  int w = tid >> 6, lane = tid & 63;
  int lq = lane & 15, quad = lane >> 4;
  int wm = w & 1, wn = w >> 1;
  long m0 = (long)blockIdx.x * 128;
  int n0 = blockIdx.y * 128;
  v4f acc[4][4];
  v4f zero = {0.f, 0.f, 0.f, 0.f};
#pragma unroll
  for (int i=0;i<4;i++)
#pragma unroll
    for (int j=0;j<4;j++) acc[i][j] = zero;

  for (int k0 = 0; k0 < K; k0 += 64){
#pragma unroll
    for (int c = 0; c < 4; c++){
      int lin = c*256 + tid;
      int row = lin >> 3, chunk = lin & 7;            // 128 rows x 8 chunks(16B)
      u16x8 av = *(const u16x8*)(A + (m0+row)*K + k0 + chunk*8);
      u16x8 bv = *(const u16x8*)(Bm + ((long)(n0+row))*K + k0 + chunk*8);
      int sw = chunk ^ (row & 7);                     // XOR swizzle vs bank conflicts
      *(u16x8*)(As + row*64 + sw*8) = av;
      *(u16x8*)(Bs + row*64 + sw*8) = bv;
    }
    __syncthreads();
#pragma unroll
    for (int s = 0; s < 2; s++){
      v8bf af[4], bf_[4];
#pragma unroll
      for (int i=0;i<4;i++){
        int row = wm*64 + i*16 + lq;
        int ch  = (s*4 + quad) ^ (row & 7);
        af[i] = __builtin_bit_cast(v8bf, *(const u16x8*)(As + row*64 + ch*8));
      }
#pragma unroll
      for (int j=0;j<4;j++){
        int row = wn*64 + j*16 + lq;
        int ch  = (s*4 + quad) ^ (row & 7);
        bf_[j] = __builtin_bit_cast(v8bf, *(const u16x8*)(Bs + row*64 + ch*8));
      }
#pragma unroll
      for (int i=0;i<4;i++)
#pragma unroll
        for (int j=0;j<4;j++)
          acc[i][j] = __builtin_amdgcn_mfma_f32_16x16x32_bf16(af[i], bf_[j], acc[i][j], 0, 0, 0);
    }
    __syncthreads();
  }
#pragma unroll
  for (int jt=0;jt<4;jt++){
    int j = n0 + wn*64 + jt*16 + lq;
    float bv = bias[j];
    int dirj = j >> 9, tg = (j >> 7) & 3, hx = j & 127;
    int tbase = ((hx>>4)*64 + quad*16 + (hx&15));   // note: quad == (b&15)>>2 below
#pragma unroll
    for (int i16=0;i16<4;i16++){
#pragma unroll
      for (int r2=0;r2<4;r2++){
        long i = m0 + wm*64 + i16*16 + quad*4 + r2;
        int b = (int)(i & 63); long l = i >> 6;
        // b = i16*16 + quad*4 + r2 (m0 multiple of 128, wm*64 ≡ 0 mod 64)
        int bg = b >> 4, qb = (b & 15) >> 2, rb = b & 3;
        long off = (((long)(dirj*4 + bg)*1024 + l) << 13)
                 + (((long)((hx>>4)*64 + qb*16 + (hx&15))) << 4) + tg*4 + rb;
        Gp[off] = f2b(acc[i16][jt][r2] + bv);
        (void)tbase;
      }
    }
  }
}

// ---------------- persistent BiLSTM layer: 8 WGs (2 dirs x 4 batch groups of 16) ----
// G': [grp][l][tid][16] bf16, z = t*4+r (gate t in i,f,g,o; r = batch within quad)
// Y: [l*64+b][256] bf16 (dir d at cols d*128). catOut: [64,256] fp32 final cells.
// sT: [l][64] softmax (or null); proj: [b][1024] attn projection (or null).
__global__ __launch_bounds__(512, 2) void lstm_layer(
    const u16* __restrict__ G, const float* __restrict__ WhhF, const float* __restrict__ WhhB,
    const float* __restrict__ h0, const float* __restrict__ c0,
    const float* __restrict__ sT, const float* __restrict__ proj,
    u16* __restrict__ Y, float* __restrict__ catOut)
{
  int blk = blockIdx.x;
  int dir = blk >> 2, bg = blk & 3, b0 = bg * 16;
  int tid = threadIdx.x, w = tid >> 6, lane = tid & 63;
  int quad = lane >> 4, lq = lane & 15;
  int hidx = w*16 + lq;                       // 0..127: this lane's hidden unit
  const float* Whh = dir ? WhhB : WhhF;

  __shared__ __align__(16) u16 hbuf[2][2048]; // h in A-frag layout, double buffered

  // Whh as B-fragments in registers: wave w owns ntiles {w+8t}, t = gate index.
  v8bf Bfrag[4][4];                           // [gate t][kstep]
#pragma unroll
  for (int t=0;t<4;t++)
#pragma unroll
    for (int ks=0;ks<4;ks++){
      int n  = (w + 8*t)*16 + lq;             // 0..511
      int kk = ks*32 + quad*8;
      u16x8 tmp;
#pragma unroll
      for (int jj=0;jj<8;jj++) tmp[jj] = f2b(Whh[n*128 + kk + jj]);
      Bfrag[t][ks] = __builtin_bit_cast(v8bf, tmp);
    }

  // per-lane cell state: batches m = quad*4+r at hidden unit hidx
  float cc[4];
  int kst = hidx >> 5, rr0 = hidx & 31, q2 = rr0 >> 3, jj0 = rr0 & 7;
  int hoff = (kst*4 + q2)*128 + jj0;          // + m*8 -> element in A-frag layout
#pragma unroll
  for (int r=0;r<4;r++){
    int m = quad*4 + r;
    cc[r] = c0[dir*8192 + (b0+m)*128 + hidx];
    hbuf[0][hoff + m*8] = f2b(h0[dir*8192 + (b0+m)*128 + hidx]);
  }

  // attention fold (LSTM2): pr[z] = 64*proj[b, dir*512 + t*128 + hidx]
  bool att = (proj != nullptr);
  float pr[16];
  if (att){
#pragma unroll
    for (int t=0;t<4;t++)
#pragma unroll
      for (int r=0;r<4;r++)
        pr[t*4+r] = 64.0f * proj[(long)(b0+quad*4+r)*1024 + dir*512 + t*128 + hidx];
  }

  const u16x8* Gp = (const u16x8*)(G + ((size_t)blk << 23)) + (size_t)tid*2;
  const float* sP = sT + b0 + quad*4;
  u16* Yb = Y + (long)(b0 + quad*4)*256 + dir*128 + hidx;

  u16x8 gbuf[2][2];
  {
    long l0 = dir ? 1023 : 0, l1 = dir ? 1022 : 1;
    gbuf[0][0] = Gp[l0*1024]; gbuf[0][1] = Gp[l0*1024 + 1];
    gbuf[1][0] = Gp[l1*1024]; gbuf[1][1] = Gp[l1*1024 + 1];
  }
  __syncthreads();

#pragma unroll 2
  for (int it = 0; it < 1024; ++it){
    int slot = it & 1;
    long l = dir ? (1023 - it) : it;
    // unpack current gates
    float gc[16];
#pragma unroll
    for (int z=0; z<16; z++) gc[z] = b2f(gbuf[slot][z>>3][z&7]);
    // prefetch it+2
    if (it < 1022){
      long l2 = dir ? (1021 - it) : (it + 2);
      gbuf[slot][0] = Gp[l2*1024];
      gbuf[slot][1] = Gp[l2*1024 + 1];
    }
    if (att){
      float4 sv = *(const float4*)(sP + l*64);
      float s4[4] = {sv.x, sv.y, sv.z, sv.w};
#pragma unroll
      for (int t=0;t<4;t++)
#pragma unroll
        for (int r=0;r<4;r++) gc[t*4+r] = fmaf(s4[r], pr[t*4+r], gc[t*4+r]);
    }
    // h fragments from LDS
    v8bf af[4];
#pragma unroll
    for (int ks=0;ks<4;ks++)
      af[ks] = __builtin_bit_cast(v8bf, *(const u16x8*)(&hbuf[slot][(ks*64 + lane)*8]));
    v4f acc[4];
#pragma unroll
    for (int t=0;t<4;t++){
      v4f tv = {gc[t*4+0], gc[t*4+1], gc[t*4+2], gc[t*4+3]};
      acc[t] = tv;
    }
#pragma unroll
    for (int ks=0;ks<4;ks++)
#pragma unroll
      for (int t=0;t<4;t++)
        acc[t] = __builtin_amdgcn_mfma_f32_16x16x32_bf16(af[ks], Bfrag[t][ks], acc[t], 0, 0, 0);

    float hv[4];
#pragma unroll
    for (int r=0;r<4;r++){
      float ig = sg(acc[0][r]);
      float fg = sg(acc[1][r]);
      float gg = th(acc[2][r]);
      float og = sg(acc[3][r]);
      float c2 = fmaf(fg, cc[r], ig*gg);
      cc[r] = c2;
      hv[r] = og * th(c2);
    }
    __hip_bfloat162 p01 = __float22bfloat162_rn(float2{hv[0], hv[1]});
    __hip_bfloat162 p23 = __float22bfloat162_rn(float2{hv[2], hv[3]});
    u16 hb[4] = { __builtin_bit_cast(u16, p01.x), __builtin_bit_cast(u16, p01.y),
                  __builtin_bit_cast(u16, p23.x), __builtin_bit_cast(u16, p23.y) };
    int pn = slot ^ 1;
    u16* yrow = Yb + l*16384;
#pragma unroll
    for (int r=0;r<4;r++){
      hbuf[pn][hoff + (quad*4+r)*8] = hb[r];
      yrow[r*256] = hb[r];
    }
    __syncthreads();
  }
  if (catOut){
#pragma unroll
    for (int r=0;r<4;r++)
      catOut[(long)(b0+quad*4+r)*256 + dir*128 + hidx] = cc[r];
  }
}

// ---------------- attention: e = fbout . catc, softmax over L, proj = catc @ Wih2[:,256:].T ----
// s written TRANSPOSED: sT[l*64 + b]
__global__ __launch_bounds__(256) void attn_kernel(
    const u16* __restrict__ y1, const float* __restrict__ catc,
    const float* __restrict__ Wih2f, const float* __restrict__ Wih2b,
    float* __restrict__ sT, float* __restrict__ proj)
{
  int b = blockIdx.x, t = threadIdx.x;
  __shared__ float catv[256];
  __shared__ float ev[1024];
  __shared__ float red[256];
  catv[t] = catc[b*256 + t];
  __syncthreads();
  float evl[4];
#pragma unroll
  for (int r2=0;r2<4;r2++){
    int l = t + r2*256;
    const u16x8* row = (const u16x8*)(y1 + ((long)l*64 + b)*256);
    float acc = 0.f;
    for (int f8=0; f8<32; f8++){
      u16x8 v = row[f8];
#pragma unroll
      for (int k=0;k<8;k++) acc += b2f(v[k]) * catv[f8*8+k];
    }
    ev[l] = acc; evl[r2] = acc;
  }
  float mx = fmaxf(fmaxf(evl[0],evl[1]), fmaxf(evl[2],evl[3]));
  red[t] = mx;
  __syncthreads();
  for (int s=128; s>0; s>>=1){ if (t < s) red[t] = fmaxf(red[t], red[t+s]); __syncthreads(); }
  float m = red[0];
  __syncthreads();
  float sum = 0.f;
#pragma unroll
  for (int r2=0;r2<4;r2++){
    int l = t + r2*256;
    float e = __expf(ev[l] - m);
    ev[l] = e; sum += e;
  }
  red[t] = sum;
  __syncthreads();
  for (int s=128; s>0; s>>=1){ if (t < s) red[t] += red[t+s]; __syncthreads(); }
  float rz = __builtin_amdgcn_rcpf(red[0]);
#pragma unroll
  for (int r2=0;r2<4;r2++){
    int l = t + r2*256;
    sT[(long)l*64 + b] = ev[l] * rz;
  }
#pragma unroll
  for (int r2=0;r2<4;r2++){
    int j = t + r2*256;
    const float* wr = (j < 512) ? (Wih2f + (long)j*512 + 256)
                                : (Wih2b + (long)(j-512)*512 + 256);
    const float4* w4 = (const float4*)wr;
    float acc = 0.f;
#pragma unroll 8
    for (int f4=0; f4<64; f4++){
      float4 v = w4[f4];
      acc += v.x*catv[f4*4+0] + v.y*catv[f4*4+1] + v.z*catv[f4*4+2] + v.w*catv[f4*4+3];
    }
    proj[b*1024 + j] = acc;
  }
}

// ---------------- feats = out2 @ Wout.T + bout ----------------
__global__ __launch_bounds__(256) void featk(const u16* __restrict__ y2,
    const float* __restrict__ Wout, const float* __restrict__ bout, float* __restrict__ feats)
{
  __shared__ float wlds[1280];
  int t = threadIdx.x;
  for (int k=t;k<1280;k+=256) wlds[k] = Wout[k];
  __syncthreads();
  long i = (long)blockIdx.x*256 + t;
  const u16x8* row = (const u16x8*)(y2 + i*256);
  float acc[5] = {0.f,0.f,0.f,0.f,0.f};
  for (int f8=0; f8<32; f8++){
    u16x8 v = row[f8];
#pragma unroll
    for (int k=0;k<8;k++){
      float x = b2f(v[k]);
      int f = f8*8 + k;
#pragma unroll
      for (int c=0;c<5;c++) acc[c] += x * wlds[c*256 + f];
    }
  }
#pragma unroll
  for (int c=0;c<5;c++) feats[i*5 + c] = acc[c] + bout[c];
}

// ---------------- CRF forward algorithm: 1 wave, thread b owns state row ----------------
__global__ void crf_kernel(const float* __restrict__ feats, const float* __restrict__ masks,
                           const float* __restrict__ trans, float* __restrict__ out)
{
  int b = threadIdx.x;  // 64
  float etr[5][5], tr4[5];
#pragma unroll
  for (int c=0;c<5;c++)
#pragma unroll
    for (int cp=0;cp<5;cp++) etr[c][cp] = __expf(trans[c*5+cp]);
#pragma unroll
  for (int cp=0;cp<5;cp++) tr4[cp] = trans[4*5+cp];   // STOP row
  float sc[5];
#pragma unroll
  for (int c=0;c<5;c++) sc[c] = (c==3) ? 0.f : -10000.f;  // START=3
  float ftn[5], mtn;
#pragma unroll
  for (int c=0;c<5;c++) ftn[c] = feats[(long)b*1024*5 + c];
  mtn = masks[b*1024];
  for (int l=0;l<1024;l++){
    float ft[5]; float mt = mtn;
#pragma unroll
    for (int c=0;c<5;c++) ft[c] = ftn[c];
    if (l < 1023){
      const float* fp = feats + ((long)b*1024 + l + 1)*5;
#pragma unroll
      for (int c=0;c<5;c++) ftn[c] = fp[c];
      mtn = masks[b*1024 + l + 1];
    }
    float m = sc[0];
#pragma unroll
    for (int c=1;c<5;c++) m = fmaxf(m, sc[c]);
    float E[5];
#pragma unroll
    for (int cp=0;cp<5;cp++) E[cp] = __expf(sc[cp] - m);
    float st[5];
#pragma unroll
    for (int c=0;c<5;c++){
      float S = E[0]*etr[c][0] + E[1]*etr[c][1] + E[2]*etr[c][2]
              + E[3]*etr[c][3] + E[4]*etr[c][4];
      st[c] = ft[c] + m + __logf(S + 1e-30f);   // clamp keeps START row finite
    }
#pragma unroll
    for (int c=0;c<5;c++) sc[c] = st[c]*mt + sc[c]*(1.f - mt);
  }
  float m2 = sc[0] + tr4[0];
#pragma unroll
  for (int cp=1;cp<5;cp++) m2 = fmaxf(m2, sc[cp] + tr4[cp]);
  float S2 = 0.f;
#pragma unroll
  for (int cp=0;cp<5;cp++) S2 += __expf(sc[cp] + tr4[cp] - m2);
  out[b] = m2 + __logf(S2);
}

// ---------------- launcher ----------------
extern "C" void kernel_launch(void* const* d_in, const int* in_sizes, int n_in,
                              void* d_out, int out_size, void* d_ws, size_t ws_size,
                              hipStream_t stream)
{
  const int*   sent  = (const int*)  d_in[0];
  const float* masks = (const float*)d_in[1];
  const float* emb   = (const float*)d_in[2];
  const float* Wih1f = (const float*)d_in[3];
  const float* Whh1f = (const float*)d_in[4];
  const float* bih1f = (const float*)d_in[5];
  const float* bhh1f = (const float*)d_in[6];
  const float* Wih1b = (const float*)d_in[7];
  const float* Whh1b = (const float*)d_in[8];
  const float* bih1b = (const float*)d_in[9];
  const float* bhh1b = (const float*)d_in[10];
  const float* Wih2f = (const float*)d_in[11];
  const float* Whh2f = (const float*)d_in[12];
  const float* bih2f = (const float*)d_in[13];
  const float* bhh2f = (const float*)d_in[14];
  const float* Wih2b = (const float*)d_in[15];
  const float* Whh2b = (const float*)d_in[16];
  const float* bih2b = (const float*)d_in[17];
  const float* bhh2b = (const float*)d_in[18];
  const float* Wout  = (const float*)d_in[19];
  const float* bout  = (const float*)d_in[20];
  const float* trans = (const float*)d_in[21];
  const float* h0    = (const float*)d_in[22];
  const float* c0    = (const float*)d_in[23];
  const float* h02   = (const float*)d_in[24];
  const float* c02   = (const float*)d_in[25];
  float* out = (float*)d_out;

  // workspace layout (aliased: X/y1/y2 share, G1/G2 share). Total ~170.7 MB.
  char* ws = (char*)d_ws;
  u16*   Ybuf  = (u16*)(ws + 0);              // 33,554,432 B: X, then y1, then y2
  u16*   Gbuf  = (u16*)(ws + 33554432);       // 134,217,728 B: G' per layer
  u16*   W1cat = (u16*)(ws + 167772160);      // 524,288 B
  u16*   WAcat = (u16*)(ws + 168296448);      // 524,288 B
  float* b1cat = (float*)(ws + 168820736);    // 4,096 B
  float* b2cat = (float*)(ws + 168824832);    // 4,096 B
  float* catcb = (float*)(ws + 168828928);    // 65,536 B
  float* sbuf  = (float*)(ws + 168894464);    // 262,144 B  (sT[l][64])
  float* projb = (float*)(ws + 169156608);    // 262,144 B
  float* featb = (float*)(ws + 169418752);    // 1,310,720 B

  conv_weights<<<1024, 256, 0, stream>>>(Wih1f, Wih1b, bih1f, bhh1f, bih1b, bhh1b,
                                         Wih2f, Wih2b, bih2f, bhh2f, bih2b, bhh2b,
                                         W1cat, WAcat, b1cat, b2cat);
  embed_gather<<<16384, 256, 0, stream>>>(sent, emb, Ybuf);
  gemm_bt<<<dim3(512, 8), 256, 0, stream>>>(Ybuf, W1cat, b1cat, Gbuf, 65536, 1024, 256);
  lstm_layer<<<8, 512, 0, stream>>>(Gbuf, Whh1f, Whh1b, h0, c0, nullptr, nullptr, Ybuf, catcb);
  attn_kernel<<<64, 256, 0, stream>>>(Ybuf, catcb, Wih2f, Wih2b, sbuf, projb);
  gemm_bt<<<dim3(512, 8), 256, 0, stream>>>(Ybuf, WAcat, b2cat, Gbuf, 65536, 1024, 256);
  lstm_layer<<<8, 512, 0, stream>>>(Gbuf, Whh2f, Whh2b, h02, c02, sbuf, projb, Ybuf, nullptr);
  featk<<<256, 256, 0, stream>>>(Ybuf, Wout, bout, featb);
  crf_kernel<<<1, 64, 0, stream>>>(featb, masks, trans, out);
}

// Round 3
// 2678.783 us; speedup vs baseline: 1.4318x; 1.1334x over previous
//
#include <hip/hip_runtime.h>
#include <hip/hip_bf16.h>

// BiLSTM-CRF forward. B=64, L=1024, E=256, H=128 (per dir), C=5, V=32000.
// R2: MFMA operand swap in LSTM: gates = Whh(A) @ h^T(B) -> D[gate_unit][batch].
// Thread owns (batch=lq, 4 contiguous hidden units): h write = 1x ds_write_b64
// (swizzled, conflict-free), Y = 1x b64 store, float4 init loads. Activations
// use shared-denominator sigma*tanh (8 transc/cell). CRF in exp domain.

typedef unsigned short u16;
typedef __bf16 v8bf __attribute__((ext_vector_type(8)));
typedef float  v4f  __attribute__((ext_vector_type(4)));
typedef unsigned short u16x8 __attribute__((ext_vector_type(8)));
typedef unsigned short u16x4 __attribute__((ext_vector_type(4)));

__device__ __forceinline__ float b2f(u16 b){
  return __builtin_bit_cast(float, ((unsigned)b) << 16);
}
__device__ __forceinline__ u16 f2b(float x){           // RNE f32->bf16
  unsigned u = __builtin_bit_cast(unsigned, x);
  unsigned r = (u + 0x7FFFu + ((u >> 16) & 1u)) >> 16;
  return (u16)r;
}

// ---------------- weight prep: concat + fp32->bf16 ----------------
__global__ __launch_bounds__(256) void conv_weights(
    const float* __restrict__ Wih1f, const float* __restrict__ Wih1b,
    const float* __restrict__ bih1f, const float* __restrict__ bhh1f,
    const float* __restrict__ bih1b, const float* __restrict__ bhh1b,
    const float* __restrict__ Wih2f, const float* __restrict__ Wih2b,
    const float* __restrict__ bih2f, const float* __restrict__ bhh2f,
    const float* __restrict__ bih2b, const float* __restrict__ bhh2b,
    u16* __restrict__ W1cat, u16* __restrict__ WAcat,
    float* __restrict__ b1cat, float* __restrict__ b2cat)
{
  int gid = blockIdx.x * 256 + threadIdx.x;   // 1024*256 = 262144
  int j = gid >> 8, e = gid & 255;
  float w1 = (j < 512) ? Wih1f[j*256 + e] : Wih1b[(j-512)*256 + e];
  float wa = (j < 512) ? Wih2f[j*512 + e] : Wih2b[(j-512)*512 + e];  // cols 0..255
  W1cat[gid] = f2b(w1);
  WAcat[gid] = f2b(wa);
  if (e == 0){
    b1cat[j] = (j < 512) ? (bih1f[j] + bhh1f[j]) : (bih1b[j-512] + bhh1b[j-512]);
    b2cat[j] = (j < 512) ? (bih2f[j] + bhh2f[j]) : (bih2b[j-512] + bhh2b[j-512]);
  }
}

// ---------------- embedding gather (flat order == reshape(L,B,E)) ----------------
__global__ __launch_bounds__(256) void embed_gather(
    const int* __restrict__ sent, const float* __restrict__ emb, u16* __restrict__ X)
{
  int w = threadIdx.x >> 6, lane = threadIdx.x & 63;
  long i = (long)blockIdx.x * 4 + w;          // row of X, 0..65535
  int idx = sent[i];
  const float4* src = (const float4*)(emb + (long)idx * 256);
  float4 v = src[lane];
  u16x4 o; o[0] = f2b(v.x); o[1] = f2b(v.y); o[2] = f2b(v.z); o[3] = f2b(v.w);
  *(u16x4*)(X + i*256 + lane*4) = o;
}

// ---- bf16 MFMA GEMM, A[MxK] rm, B[NxK] rm, +bias; writes G'[grp][l][thr][16] ----
// element (i,j): l=i>>6, b=i&63; dirj=j>>9, tg=(j>>7)&3, hx=j&127
// grp = dirj*4+(b>>4); thr = (hx>>4)*64 + ((hx>>2)&3)*16 + (b&15); z = tg*4+(hx&3)
__global__ __launch_bounds__(256) void gemm_bt(
    const u16* __restrict__ A, const u16* __restrict__ Bm,
    const float* __restrict__ bias, u16* __restrict__ Gp,
    int M, int N, int K)
{
  __shared__ __align__(16) u16 As[128*64];
  __shared__ __align__(16) u16 Bs[128*64];
  int tid = threadIdx.x;
  int w = tid >> 6, lane = tid & 63;
  int lq = lane & 15, quad = lane >> 4;
  int wm = w & 1, wn = w >> 1;
  long m0 = (long)blockIdx.x * 128;
  int n0 = blockIdx.y * 128;
  v4f acc[4][4];
  v4f zero = {0.f, 0.f, 0.f, 0.f};
#pragma unroll
  for (int i=0;i<4;i++)
#pragma unroll
    for (int j=0;j<4;j++) acc[i][j] = zero;

  for (int k0 = 0; k0 < K; k0 += 64){
#pragma unroll
    for (int c = 0; c < 4; c++){
      int lin = c*256 + tid;
      int row = lin >> 3, chunk = lin & 7;            // 128 rows x 8 chunks(16B)
      u16x8 av = *(const u16x8*)(A + (m0+row)*K + k0 + chunk*8);
      u16x8 bv = *(const u16x8*)(Bm + ((long)(n0+row))*K + k0 + chunk*8);
      int sw = chunk ^ (row & 7);                     // XOR swizzle vs bank conflicts
      *(u16x8*)(As + row*64 + sw*8) = av;
      *(u16x8*)(Bs + row*64 + sw*8) = bv;
    }
    __syncthreads();
#pragma unroll
    for (int s = 0; s < 2; s++){
      v8bf af[4], bf_[4];
#pragma unroll
      for (int i=0;i<4;i++){
        int row = wm*64 + i*16 + lq;
        int ch  = (s*4 + quad) ^ (row & 7);
        af[i] = __builtin_bit_cast(v8bf, *(const u16x8*)(As + row*64 + ch*8));
      }
#pragma unroll
      for (int j=0;j<4;j++){
        int row = wn*64 + j*16 + lq;
        int ch  = (s*4 + quad) ^ (row & 7);
        bf_[j] = __builtin_bit_cast(v8bf, *(const u16x8*)(Bs + row*64 + ch*8));
      }
#pragma unroll
      for (int i=0;i<4;i++)
#pragma unroll
        for (int j=0;j<4;j++)
          acc[i][j] = __builtin_amdgcn_mfma_f32_16x16x32_bf16(af[i], bf_[j], acc[i][j], 0, 0, 0);
    }
    __syncthreads();
  }
#pragma unroll
  for (int jt=0;jt<4;jt++){
    int j = n0 + wn*64 + jt*16 + lq;
    float bv = bias[j];
    int dirj = j >> 9, tg = (j >> 7) & 3, hx = j & 127;
    int thrP = (hx>>4)*64 + ((hx>>2)&3)*16;
    int z = tg*4 + (hx&3);
#pragma unroll
    for (int i16=0;i16<4;i16++){
#pragma unroll
      for (int r2=0;r2<4;r2++){
        long i = m0 + wm*64 + i16*16 + quad*4 + r2;
        int bb = (int)(i & 63); long l = i >> 6;
        long off = (((long)(dirj*4 + (bb>>4))*1024 + l) << 13)
                 + (long)(thrP + (bb&15))*16 + z;
        Gp[off] = f2b(acc[i16][jt][r2] + bv);
      }
    }
  }
}

// ---------------- persistent BiLSTM layer: 8 WGs (2 dirs x 4 batch groups of 16) ----
// G': [grp][l][thr][16] bf16, z = t*4+r. Thread (w,quad,lq): batch=b0+lq,
// hidden units hu0..hu0+3 (hu0 = w*16+quad*4), all four gates.
// Y: [l*64+b][256] bf16 (dir d at cols d*128). catOut: [64,256] fp32 final cells.
__global__ __launch_bounds__(512, 2) void lstm_layer(
    const u16* __restrict__ G, const float* __restrict__ WhhF, const float* __restrict__ WhhB,
    const float* __restrict__ h0, const float* __restrict__ c0,
    const float* __restrict__ sT, const float* __restrict__ proj,
    u16* __restrict__ Y, float* __restrict__ catOut)
{
  int blk = blockIdx.x;
  int dir = blk >> 2, bg = blk & 3, b0 = bg * 16;
  int tid = threadIdx.x, w = tid >> 6, lane = tid & 63;
  int quad = lane >> 4, lq = lane & 15;
  int hu0 = w*16 + quad*4;
  int batch = b0 + lq;
  const float* Whh = dir ? WhhB : WhhF;

  __shared__ __align__(16) u16 hbuf[2][2048]; // h[batch][hu], 16B-chunk XOR swizzle

  // Whh as A-frags in registers: wave w owns tiles {t*8+w}, t = gate index.
  // A[m=lq][k=ks*32+quad*8+j] for tile rows (t*8+w)*16+lq.
  v8bf Af[4][4];
#pragma unroll
  for (int t=0;t<4;t++)
#pragma unroll
    for (int ks=0;ks<4;ks++){
      int n  = (t*8 + w)*16 + lq;             // 0..511 gate-unit row
      int kk = ks*32 + quad*8;
      u16x8 tmp;
#pragma unroll
      for (int jj=0;jj<8;jj++) tmp[jj] = f2b(Whh[n*128 + kk + jj]);
      Af[t][ks] = __builtin_bit_cast(v8bf, tmp);
    }

  // LDS addresses (u16 units), 16B-chunk swizzle: chunk c of batch b at c^(b&15)
  int wOff = lq*128 + (((w*2 + (quad>>1)) ^ lq) * 8) + (quad&1)*4;
  int rOff[4];
#pragma unroll
  for (int ks=0;ks<4;ks++) rOff[ks] = lq*128 + (((ks*4 + quad) ^ lq) * 8);

  float cc[4];
  {
    float4 c4 = *(const float4*)(c0 + dir*8192 + batch*128 + hu0);
    cc[0]=c4.x; cc[1]=c4.y; cc[2]=c4.z; cc[3]=c4.w;
    float4 h4 = *(const float4*)(h0 + dir*8192 + batch*128 + hu0);
    u16x4 hp; hp[0]=f2b(h4.x); hp[1]=f2b(h4.y); hp[2]=f2b(h4.z); hp[3]=f2b(h4.w);
    *(u16x4*)(&hbuf[0][wOff]) = hp;
  }

  // attention fold (LSTM2): pr[t*4+r] = 64*proj[batch, dir*512 + t*128 + hu0+r]
  bool att = (proj != nullptr);
  float pr[16];
  if (att){
#pragma unroll
    for (int t=0;t<4;t++){
      float4 p4 = *(const float4*)(proj + (long)batch*1024 + dir*512 + t*128 + hu0);
      pr[t*4+0]=64.f*p4.x; pr[t*4+1]=64.f*p4.y; pr[t*4+2]=64.f*p4.z; pr[t*4+3]=64.f*p4.w;
    }
  }

  const u16x8* Gp = (const u16x8*)(G + ((size_t)blk << 23)) + (size_t)tid*2;
  long dl = dir ? -1 : 1;
  long l0 = dir ? 1023 : 0;
  u16x8 gbuf[2][2];
  gbuf[0][0] = Gp[(size_t)l0*1024];        gbuf[0][1] = Gp[(size_t)l0*1024 + 1];
  gbuf[1][0] = Gp[(size_t)(l0+dl)*1024];   gbuf[1][1] = Gp[(size_t)(l0+dl)*1024 + 1];
  const u16x8* gpf = Gp + (l0 + 2*dl)*1024;   // prefetch ptr (may run 2 past end: ws-internal, unused)
  u16* yp = Y + (l0*64 + batch)*256 + dir*128 + hu0;
  const float* sp = att ? (sT + l0*64 + batch) : nullptr;
  __syncthreads();

  const float L2E  = 1.4426950408889634f;
  const float NL2E = -1.4426950408889634f;
  const float N2L2E = -2.8853900817779268f;

#pragma unroll 2
  for (int it = 0; it < 1024; ++it){
    int slot = it & 1;
    float gc[16];
#pragma unroll
    for (int z=0; z<16; z++) gc[z] = b2f(gbuf[slot][z>>3][z&7]);
    gbuf[slot][0] = gpf[0];                 // prefetch it+2 (same parity slot)
    gbuf[slot][1] = gpf[1];
    gpf += dl*1024;
    if (att){
      float s = *sp;
      sp += dl*64;
#pragma unroll
      for (int z=0; z<16; z++) gc[z] = fmaf(s, pr[z], gc[z]);
    }
    v8bf bh[4];
#pragma unroll
    for (int ks=0;ks<4;ks++)
      bh[ks] = __builtin_bit_cast(v8bf, *(const u16x8*)(&hbuf[slot][rOff[ks]]));
    v4f acc[4];
#pragma unroll
    for (int t=0;t<4;t++){
      v4f tv = {gc[t*4+0], gc[t*4+1], gc[t*4+2], gc[t*4+3]};
      acc[t] = tv;
    }
#pragma unroll
    for (int ks=0;ks<4;ks++)
#pragma unroll
      for (int t=0;t<4;t++)
        acc[t] = __builtin_amdgcn_mfma_f32_16x16x32_bf16(Af[t][ks], bh[ks], acc[t], 0, 0, 0);

    u16x4 hp;
#pragma unroll
    for (int r=0;r<4;r++){
      float i_ = acc[0][r], f_ = acc[1][r], g_ = acc[2][r], o_ = acc[3][r];
      float ef = __builtin_amdgcn_exp2f(f_ * NL2E);
      float ei = __builtin_amdgcn_exp2f(i_ * NL2E);
      float eg = __builtin_amdgcn_exp2f(fminf(g_ * N2L2E, 115.0f));
      float sf = __builtin_amdgcn_rcpf(1.0f + ef);
      float p  = (1.0f - eg) * __builtin_amdgcn_rcpf((1.0f + ei) * (1.0f + eg));
      float c2 = fmaf(cc[r], sf, p);
      cc[r] = c2;
      float eo = __builtin_amdgcn_exp2f(o_ * NL2E);
      float ec = __builtin_amdgcn_exp2f(fminf(c2 * N2L2E, 115.0f));
      float hv = (1.0f - ec) * __builtin_amdgcn_rcpf((1.0f + eo) * (1.0f + ec));
      hp[r] = f2b(hv);
    }
    *(u16x4*)(&hbuf[slot^1][wOff]) = hp;
    *(u16x4*)yp = hp;
    yp += dl*16384;
    __syncthreads();
  }
  (void)L2E;
  if (catOut){
    float4 cv; cv.x=cc[0]; cv.y=cc[1]; cv.z=cc[2]; cv.w=cc[3];
    *(float4*)(catOut + (long)batch*256 + dir*128 + hu0) = cv;
  }
}

// ---------------- attention: e = fbout . catc, softmax over L, proj = catc @ Wih2[:,256:].T ----
// s written TRANSPOSED: sT[l*64 + b]
__global__ __launch_bounds__(256) void attn_kernel(
    const u16* __restrict__ y1, const float* __restrict__ catc,
    const float* __restrict__ Wih2f, const float* __restrict__ Wih2b,
    float* __restrict__ sT, float* __restrict__ proj)
{
  int b = blockIdx.x, t = threadIdx.x;
  __shared__ float catv[256];
  __shared__ float ev[1024];
  __shared__ float red[256];
  catv[t] = catc[b*256 + t];
  __syncthreads();
  float evl[4];
#pragma unroll
  for (int r2=0;r2<4;r2++){
    int l = t + r2*256;
    const u16x8* row = (const u16x8*)(y1 + ((long)l*64 + b)*256);
    float acc = 0.f;
    for (int f8=0; f8<32; f8++){
      u16x8 v = row[f8];
#pragma unroll
      for (int k=0;k<8;k++) acc += b2f(v[k]) * catv[f8*8+k];
    }
    ev[l] = acc; evl[r2] = acc;
  }
  float mx = fmaxf(fmaxf(evl[0],evl[1]), fmaxf(evl[2],evl[3]));
  red[t] = mx;
  __syncthreads();
  for (int s=128; s>0; s>>=1){ if (t < s) red[t] = fmaxf(red[t], red[t+s]); __syncthreads(); }
  float m = red[0];
  __syncthreads();
  float sum = 0.f;
#pragma unroll
  for (int r2=0;r2<4;r2++){
    int l = t + r2*256;
    float e = __expf(ev[l] - m);
    ev[l] = e; sum += e;
  }
  red[t] = sum;
  __syncthreads();
  for (int s=128; s>0; s>>=1){ if (t < s) red[t] += red[t+s]; __syncthreads(); }
  float rz = __builtin_amdgcn_rcpf(red[0]);
#pragma unroll
  for (int r2=0;r2<4;r2++){
    int l = t + r2*256;
    sT[(long)l*64 + b] = ev[l] * rz;
  }
#pragma unroll
  for (int r2=0;r2<4;r2++){
    int j = t + r2*256;
    const float* wr = (j < 512) ? (Wih2f + (long)j*512 + 256)
                                : (Wih2b + (long)(j-512)*512 + 256);
    const float4* w4 = (const float4*)wr;
    float acc = 0.f;
#pragma unroll 8
    for (int f4=0; f4<64; f4++){
      float4 v = w4[f4];
      acc += v.x*catv[f4*4+0] + v.y*catv[f4*4+1] + v.z*catv[f4*4+2] + v.w*catv[f4*4+3];
    }
    proj[b*1024 + j] = acc;
  }
}

// ---------------- feats = out2 @ Wout.T + bout ----------------
__global__ __launch_bounds__(256) void featk(const u16* __restrict__ y2,
    const float* __restrict__ Wout, const float* __restrict__ bout, float* __restrict__ feats)
{
  __shared__ float wlds[1280];
  int t = threadIdx.x;
  for (int k=t;k<1280;k+=256) wlds[k] = Wout[k];
  __syncthreads();
  long i = (long)blockIdx.x*256 + t;
  const u16x8* row = (const u16x8*)(y2 + i*256);
  float acc[5] = {0.f,0.f,0.f,0.f,0.f};
  for (int f8=0; f8<32; f8++){
    u16x8 v = row[f8];
#pragma unroll
    for (int k=0;k<8;k++){
      float x = b2f(v[k]);
      int f = f8*8 + k;
#pragma unroll
      for (int c=0;c<5;c++) acc[c] += x * wlds[c*256 + f];
    }
  }
#pragma unroll
  for (int c=0;c<5;c++) feats[i*5 + c] = acc[c] + bout[c];
}

// ---------------- CRF forward, exp domain: sc[c] = M + ln E[c] ----------------
// Renorm each step by exact power of 2 (exponent extraction) -> no log in loop.
__global__ void crf_kernel(const float* __restrict__ feats, const float* __restrict__ masks,
                           const float* __restrict__ trans, float* __restrict__ out)
{
  int b = threadIdx.x;  // 64
  float etr[5][5], tr4[5];
#pragma unroll
  for (int c=0;c<5;c++)
#pragma unroll
    for (int cp=0;cp<5;cp++) etr[c][cp] = __expf(trans[c*5+cp]);  // e^-10000 -> 0
#pragma unroll
  for (int cp=0;cp<5;cp++) tr4[cp] = trans[4*5+cp];   // STOP row
  float E[5] = {0.f, 0.f, 0.f, 1.f, 0.f};             // exp(sc), START=3
  float M = 0.f;
  const float* fpB = feats + (long)b*5120;
  float ftn[5], mtn;
#pragma unroll
  for (int c=0;c<5;c++) ftn[c] = fpB[c];
  mtn = masks[b*1024];
  for (int l=0;l<1024;l++){
    float ft[5]; float mt = mtn;
#pragma unroll
    for (int c=0;c<5;c++) ft[c] = ftn[c];
    if (l < 1023){
      const float* fp = fpB + (l + 1)*5;
#pragma unroll
      for (int c=0;c<5;c++) ftn[c] = fp[c];
      mtn = masks[b*1024 + l + 1];
    }
    float En[5];
#pragma unroll
    for (int c=0;c<5;c++){
      float S = E[0]*etr[c][0];
#pragma unroll
      for (int cp=1;cp<5;cp++) S = fmaf(E[cp], etr[c][cp], S);
      En[c] = S * __expf(ft[c]);
    }
    bool take = (mt > 0.5f);
#pragma unroll
    for (int c=0;c<5;c++) E[c] = take ? En[c] : E[c];
    // exact power-of-2 renorm
    float mx = fmaxf(fmaxf(fmaxf(E[0],E[1]), fmaxf(E[2],E[3])), E[4]);
    int k = (int)((__builtin_bit_cast(unsigned, mx) >> 23) & 0xFFu) - 127;
    float s = __builtin_bit_cast(float, (unsigned)(127 - k) << 23);
#pragma unroll
    for (int c=0;c<5;c++) E[c] *= s;
    M = fmaf((float)k, 0.6931471805599453f, M);
  }
  float Sf = 0.f;
#pragma unroll
  for (int cp=0;cp<5;cp++) Sf = fmaf(E[cp], __expf(tr4[cp]), Sf);
  out[b] = M + __logf(Sf);
}

// ---------------- launcher ----------------
extern "C" void kernel_launch(void* const* d_in, const int* in_sizes, int n_in,
                              void* d_out, int out_size, void* d_ws, size_t ws_size,
                              hipStream_t stream)
{
  const int*   sent  = (const int*)  d_in[0];
  const float* masks = (const float*)d_in[1];
  const float* emb   = (const float*)d_in[2];
  const float* Wih1f = (const float*)d_in[3];
  const float* Whh1f = (const float*)d_in[4];
  const float* bih1f = (const float*)d_in[5];
  const float* bhh1f = (const float*)d_in[6];
  const float* Wih1b = (const float*)d_in[7];
  const float* Whh1b = (const float*)d_in[8];
  const float* bih1b = (const float*)d_in[9];
  const float* bhh1b = (const float*)d_in[10];
  const float* Wih2f = (const float*)d_in[11];
  const float* Whh2f = (const float*)d_in[12];
  const float* bih2f = (const float*)d_in[13];
  const float* bhh2f = (const float*)d_in[14];
  const float* Wih2b = (const float*)d_in[15];
  const float* Whh2b = (const float*)d_in[16];
  const float* bih2b = (const float*)d_in[17];
  const float* bhh2b = (const float*)d_in[18];
  const float* Wout  = (const float*)d_in[19];
  const float* bout  = (const float*)d_in[20];
  const float* trans = (const float*)d_in[21];
  const float* h0    = (const float*)d_in[22];
  const float* c0    = (const float*)d_in[23];
  const float* h02   = (const float*)d_in[24];
  const float* c02   = (const float*)d_in[25];
  float* out = (float*)d_out;

  // workspace layout (aliased: X/y1/y2 share, G per layer shares). ~170.7 MB.
  char* ws = (char*)d_ws;
  u16*   Ybuf  = (u16*)(ws + 0);              // 33,554,432 B: X, then y1, then y2
  u16*   Gbuf  = (u16*)(ws + 33554432);       // 134,217,728 B: G' per layer
  u16*   W1cat = (u16*)(ws + 167772160);      // 524,288 B
  u16*   WAcat = (u16*)(ws + 168296448);      // 524,288 B
  float* b1cat = (float*)(ws + 168820736);    // 4,096 B
  float* b2cat = (float*)(ws + 168824832);    // 4,096 B
  float* catcb = (float*)(ws + 168828928);    // 65,536 B
  float* sbuf  = (float*)(ws + 168894464);    // 262,144 B  (sT[l][64])
  float* projb = (float*)(ws + 169156608);    // 262,144 B
  float* featb = (float*)(ws + 169418752);    // 1,310,720 B

  conv_weights<<<1024, 256, 0, stream>>>(Wih1f, Wih1b, bih1f, bhh1f, bih1b, bhh1b,
                                         Wih2f, Wih2b, bih2f, bhh2f, bih2b, bhh2b,
                                         W1cat, WAcat, b1cat, b2cat);
  embed_gather<<<16384, 256, 0, stream>>>(sent, emb, Ybuf);
  gemm_bt<<<dim3(512, 8), 256, 0, stream>>>(Ybuf, W1cat, b1cat, Gbuf, 65536, 1024, 256);
  lstm_layer<<<8, 512, 0, stream>>>(Gbuf, Whh1f, Whh1b, h0, c0, nullptr, nullptr, Ybuf, catcb);
  attn_kernel<<<64, 256, 0, stream>>>(Ybuf, catcb, Wih2f, Wih2b, sbuf, projb);
  gemm_bt<<<dim3(512, 8), 256, 0, stream>>>(Ybuf, WAcat, b2cat, Gbuf, 65536, 1024, 256);
  lstm_layer<<<8, 512, 0, stream>>>(Gbuf, Whh2f, Whh2b, h02, c02, sbuf, projb, Ybuf, nullptr);
  featk<<<256, 256, 0, stream>>>(Ybuf, Wout, bout, featb);
  crf_kernel<<<1, 64, 0, stream>>>(featb, masks, trans, out);
}

// Round 5
// 2602.312 us; speedup vs baseline: 1.4739x; 1.0294x over previous
//
#include <hip/hip_runtime.h>
#include <hip/hip_bf16.h>

// BiLSTM-CRF forward. B=64, L=1024, E=256, H=128 (per dir), C=5, V=32000.
// R3b: LSTM layer at 1024 threads/WG (16 waves = 4/SIMD for latency hiding).
// Gate-interleaved A tiles: tile row m = gate(m&3) of unit u0+2*(m>>2)+tau, so
// D row=quad*4+r gives each thread ALL 4 gates of 2 units (v*8+2q, +1).
// G'' layout [grp][l][tid0..1023][8]: one dwordx4 gate load per thread/step.
// (R4 fix: manual bf16 pair packing instead of bit_cast of __hip_bfloat162.)

typedef unsigned short u16;
typedef unsigned int u32;
typedef __bf16 v8bf __attribute__((ext_vector_type(8)));
typedef float  v4f  __attribute__((ext_vector_type(4)));
typedef unsigned short u16x8 __attribute__((ext_vector_type(8)));
typedef unsigned short u16x4 __attribute__((ext_vector_type(4)));

__device__ __forceinline__ float b2f(u16 b){
  return __builtin_bit_cast(float, ((unsigned)b) << 16);
}
__device__ __forceinline__ u16 f2b(float x){           // RNE f32->bf16
  unsigned u = __builtin_bit_cast(unsigned, x);
  unsigned r = (u + 0x7FFFu + ((u >> 16) & 1u)) >> 16;
  return (u16)r;
}

// ---------------- weight prep: concat + fp32->bf16 ----------------
__global__ __launch_bounds__(256) void conv_weights(
    const float* __restrict__ Wih1f, const float* __restrict__ Wih1b,
    const float* __restrict__ bih1f, const float* __restrict__ bhh1f,
    const float* __restrict__ bih1b, const float* __restrict__ bhh1b,
    const float* __restrict__ Wih2f, const float* __restrict__ Wih2b,
    const float* __restrict__ bih2f, const float* __restrict__ bhh2f,
    const float* __restrict__ bih2b, const float* __restrict__ bhh2b,
    u16* __restrict__ W1cat, u16* __restrict__ WAcat,
    float* __restrict__ b1cat, float* __restrict__ b2cat)
{
  int gid = blockIdx.x * 256 + threadIdx.x;   // 1024*256 = 262144
  int j = gid >> 8, e = gid & 255;
  float w1 = (j < 512) ? Wih1f[j*256 + e] : Wih1b[(j-512)*256 + e];
  float wa = (j < 512) ? Wih2f[j*512 + e] : Wih2b[(j-512)*512 + e];  // cols 0..255
  W1cat[gid] = f2b(w1);
  WAcat[gid] = f2b(wa);
  if (e == 0){
    b1cat[j] = (j < 512) ? (bih1f[j] + bhh1f[j]) : (bih1b[j-512] + bhh1b[j-512]);
    b2cat[j] = (j < 512) ? (bih2f[j] + bhh2f[j]) : (bih2b[j-512] + bhh2b[j-512]);
  }
}

// ---------------- embedding gather (flat order == reshape(L,B,E)) ----------------
__global__ __launch_bounds__(256) void embed_gather(
    const int* __restrict__ sent, const float* __restrict__ emb, u16* __restrict__ X)
{
  int w = threadIdx.x >> 6, lane = threadIdx.x & 63;
  long i = (long)blockIdx.x * 4 + w;          // row of X, 0..65535
  int idx = sent[i];
  const float4* src = (const float4*)(emb + (long)idx * 256);
  float4 v = src[lane];
  u16x4 o; o[0] = f2b(v.x); o[1] = f2b(v.y); o[2] = f2b(v.z); o[3] = f2b(v.w);
  *(u16x4*)(X + i*256 + lane*4) = o;
}

// ---- bf16 MFMA GEMM, A[MxK] rm, B[NxK] rm, +bias; writes G''[grp][l][thr][8] ----
// element (i,j): l=i>>6, b=i&63; dirj=j>>9, g=(j>>7)&3 (gate), u=j&127 (unit)
// v=u>>3, tau=u&1, q=(u>>1)&3; grp=dirj*4+(b>>4); thr=v*64+q*16+(b&15); z=tau*4+g
__global__ __launch_bounds__(256) void gemm_bt(
    const u16* __restrict__ A, const u16* __restrict__ Bm,
    const float* __restrict__ bias, u16* __restrict__ Gp,
    int M, int N, int K)
{
  __shared__ __align__(16) u16 As[128*64];
  __shared__ __align__(16) u16 Bs[128*64];
  int tid = threadIdx.x;
  int w = tid >> 6, lane = tid & 63;
  int lq = lane & 15, quad = lane >> 4;
  int wm = w & 1, wn = w >> 1;
  long m0 = (long)blockIdx.x * 128;
  int n0 = blockIdx.y * 128;
  v4f acc[4][4];
  v4f zero = {0.f, 0.f, 0.f, 0.f};
#pragma unroll
  for (int i=0;i<4;i++)
#pragma unroll
    for (int j=0;j<4;j++) acc[i][j] = zero;

  for (int k0 = 0; k0 < K; k0 += 64){
#pragma unroll
    for (int c = 0; c < 4; c++){
      int lin = c*256 + tid;
      int row = lin >> 3, chunk = lin & 7;            // 128 rows x 8 chunks(16B)
      u16x8 av = *(const u16x8*)(A + (m0+row)*K + k0 + chunk*8);
      u16x8 bv = *(const u16x8*)(Bm + ((long)(n0+row))*K + k0 + chunk*8);
      int sw = chunk ^ (row & 7);                     // XOR swizzle vs bank conflicts
      *(u16x8*)(As + row*64 + sw*8) = av;
      *(u16x8*)(Bs + row*64 + sw*8) = bv;
    }
    __syncthreads();
#pragma unroll
    for (int s = 0; s < 2; s++){
      v8bf af[4], bf_[4];
#pragma unroll
      for (int i=0;i<4;i++){
        int row = wm*64 + i*16 + lq;
        int ch  = (s*4 + quad) ^ (row & 7);
        af[i] = __builtin_bit_cast(v8bf, *(const u16x8*)(As + row*64 + ch*8));
      }
#pragma unroll
      for (int j=0;j<4;j++){
        int row = wn*64 + j*16 + lq;
        int ch  = (s*4 + quad) ^ (row & 7);
        bf_[j] = __builtin_bit_cast(v8bf, *(const u16x8*)(Bs + row*64 + ch*8));
      }
#pragma unroll
      for (int i=0;i<4;i++)
#pragma unroll
        for (int j=0;j<4;j++)
          acc[i][j] = __builtin_amdgcn_mfma_f32_16x16x32_bf16(af[i], bf_[j], acc[i][j], 0, 0, 0);
    }
    __syncthreads();
  }
#pragma unroll
  for (int jt=0;jt<4;jt++){
    int j = n0 + wn*64 + jt*16 + lq;
    float bv = bias[j];
    int dirj = j >> 9, g = (j >> 7) & 3, u = j & 127;
    int v = u >> 3, tau = u & 1, q = (u >> 1) & 3;
    int thrP = v*64 + q*16;
    int z = tau*4 + g;
#pragma unroll
    for (int i16=0;i16<4;i16++){
#pragma unroll
      for (int r2=0;r2<4;r2++){
        long i = m0 + wm*64 + i16*16 + quad*4 + r2;
        int bb = (int)(i & 63); long l = i >> 6;
        long off = ((long)(dirj*4 + (bb>>4)) << 23) + (l << 13)
                 + (long)(thrP + (bb&15))*8 + z;
        Gp[off] = f2b(acc[i16][jt][r2] + bv);
      }
    }
  }
}

// ---------------- persistent BiLSTM layer: 8 WGs x 1024 thr (2 dirs x 4 bgroups) ----
// Thread (v=tid>>6, quad, lq): batch=b0+lq, units U0=v*8+2*quad and U0+1, all gates.
// A tiles (tau=0,1): row m = gate(m&3) of unit v*8+tau+2*(m>>2).
// G'': [grp][l][tid][8] bf16, z=tau*4+gate.
// Y: [l*64+b][256] bf16 (dir d at cols d*128). catOut: [64,256] fp32 final cells.
__global__ __launch_bounds__(1024, 4) void lstm_layer(
    const u16* __restrict__ G, const float* __restrict__ WhhF, const float* __restrict__ WhhB,
    const float* __restrict__ h0, const float* __restrict__ c0,
    const float* __restrict__ sT, const float* __restrict__ proj,
    u16* __restrict__ Y, float* __restrict__ catOut)
{
  int blk = blockIdx.x;
  int dir = blk >> 2, bg = blk & 3, b0 = bg * 16;
  int tid = threadIdx.x, v = tid >> 6, lane = tid & 63;
  int quad = lane >> 4, lq = lane & 15;
  int U0 = v*8 + 2*quad;
  int batch = b0 + lq;
  const float* Whh = dir ? WhhB : WhhF;

  __shared__ __align__(16) u16 hbuf[2][2048]; // h[batch][unit], 16B-chunk XOR swizzle

  // A-frags in registers: lane holds A[m=lq][k=ks*32+quad*8+j]
  // tile tau row m: gate = m&3, unit = v*8 + tau + 2*(m>>2)
  v8bf Af[2][4];
  {
    int gate = lq & 3;
#pragma unroll
    for (int tau=0;tau<2;tau++){
      int unit = v*8 + tau + 2*(lq>>2);
      const float* wr = Whh + (long)(gate*128 + unit)*128;
#pragma unroll
      for (int ks=0;ks<4;ks++){
        u16x8 tmp;
#pragma unroll
        for (int jj=0;jj<8;jj++) tmp[jj] = f2b(wr[ks*32 + quad*8 + jj]);
        Af[tau][ks] = __builtin_bit_cast(v8bf, tmp);
      }
    }
  }

  // LDS addrs (u16 units): row=batch lq (128 u16), chunk c at (c^lq), 8 u16 each
  int wOff = lq*128 + ((v ^ lq) * 8) + 2*quad;          // write: units U0,U0+1 (u32)
  int rOff[4];
#pragma unroll
  for (int ks=0;ks<4;ks++) rOff[ks] = lq*128 + (((ks*4 + quad) ^ lq) * 8);

  float cc[2];
  {
    float2 c2v = *(const float2*)(c0 + dir*8192 + batch*128 + U0);
    cc[0]=c2v.x; cc[1]=c2v.y;
    float2 h2v = *(const float2*)(h0 + dir*8192 + batch*128 + U0);
    u16 hp0 = f2b(h2v.x), hp1 = f2b(h2v.y);
    *(u32*)(&hbuf[0][wOff]) = (u32)hp0 | ((u32)hp1 << 16);
  }

  // attention fold (LSTM2): pr[tau*4+g] = 64*proj[batch, dir*512 + g*128 + U0+tau]
  bool att = (proj != nullptr);
  float pr[8];
  if (att){
#pragma unroll
    for (int g=0;g<4;g++){
      float2 p2 = *(const float2*)(proj + (long)batch*1024 + dir*512 + g*128 + U0);
      pr[0*4+g] = 64.f*p2.x;
      pr[1*4+g] = 64.f*p2.y;
    }
  }

  const u16x8* Gp = (const u16x8*)(G + ((size_t)blk << 23)) + tid;
  long dl = dir ? -1 : 1;
  long l0 = dir ? 1023 : 0;
  u16x8 gbuf[2];
  gbuf[0] = Gp[l0 << 10];
  gbuf[1] = Gp[(l0 + dl) << 10];
  const u16x8* gpf = Gp + ((l0 + 2*dl) << 10);  // runs 2 past end: ws-internal, unused
  u16* yp = Y + (l0*64 + batch)*256 + dir*128 + U0;
  const float* sp = att ? (sT + l0*64 + batch) : nullptr;
  __syncthreads();

  const float NL2E = -1.4426950408889634f;
  const float N2L2E = -2.8853900817779268f;

#pragma unroll 2
  for (int it = 0; it < 1024; ++it){
    int slot = it & 1;
    float gc[8];
#pragma unroll
    for (int z=0; z<8; z++) gc[z] = b2f(gbuf[slot][z]);
    gbuf[slot] = *gpf;                 // prefetch it+2 (same parity slot)
    gpf += dl << 10;
    // h fragments from LDS (B operand, shared data across waves)
    v8bf bh[4];
#pragma unroll
    for (int ks=0;ks<4;ks++)
      bh[ks] = __builtin_bit_cast(v8bf, *(const u16x8*)(&hbuf[slot][rOff[ks]]));
    v4f acc[2];
#pragma unroll
    for (int tau=0;tau<2;tau++){
      v4f tv = {gc[tau*4+0], gc[tau*4+1], gc[tau*4+2], gc[tau*4+3]};
      acc[tau] = tv;
    }
#pragma unroll
    for (int ks=0;ks<4;ks++)
#pragma unroll
      for (int tau=0;tau<2;tau++)
        acc[tau] = __builtin_amdgcn_mfma_f32_16x16x32_bf16(Af[tau][ks], bh[ks], acc[tau], 0, 0, 0);

    if (att){   // rank-1 attention add, post-MFMA (commutes: C-operand addition)
      float s = *sp;
      sp += dl*64;
#pragma unroll
      for (int tau=0;tau<2;tau++)
#pragma unroll
        for (int g=0;g<4;g++) acc[tau][g] = fmaf(s, pr[tau*4+g], acc[tau][g]);
    }

    float hv[2];
#pragma unroll
    for (int tau=0;tau<2;tau++){
      float i_ = acc[tau][0], f_ = acc[tau][1], g_ = acc[tau][2], o_ = acc[tau][3];
      float ef = __builtin_amdgcn_exp2f(f_ * NL2E);
      float ei = __builtin_amdgcn_exp2f(i_ * NL2E);
      float eg = __builtin_amdgcn_exp2f(fminf(g_ * N2L2E, 115.0f));
      float sf = __builtin_amdgcn_rcpf(1.0f + ef);
      float p  = (1.0f - eg) * __builtin_amdgcn_rcpf((1.0f + ei) * (1.0f + eg));
      float c2 = fmaf(cc[tau], sf, p);
      cc[tau] = c2;
      float eo = __builtin_amdgcn_exp2f(o_ * NL2E);
      float ec = __builtin_amdgcn_exp2f(fminf(c2 * N2L2E, 115.0f));
      hv[tau] = (1.0f - ec) * __builtin_amdgcn_rcpf((1.0f + eo) * (1.0f + ec));
    }
    u32 hw = (u32)f2b(hv[0]) | ((u32)f2b(hv[1]) << 16);
    *(u32*)(&hbuf[slot^1][wOff]) = hw;
    *(u32*)yp = hw;
    yp += dl*16384;
    __syncthreads();
  }
  if (catOut){
    float2 cv; cv.x=cc[0]; cv.y=cc[1];
    *(float2*)(catOut + (long)batch*256 + dir*128 + U0) = cv;
  }
}

// ---------------- attention: e = fbout . catc, softmax over L, proj = catc @ Wih2[:,256:].T ----
// s written TRANSPOSED: sT[l*64 + b]
__global__ __launch_bounds__(256) void attn_kernel(
    const u16* __restrict__ y1, const float* __restrict__ catc,
    const float* __restrict__ Wih2f, const float* __restrict__ Wih2b,
    float* __restrict__ sT, float* __restrict__ proj)
{
  int b = blockIdx.x, t = threadIdx.x;
  __shared__ float catv[256];
  __shared__ float ev[1024];
  __shared__ float red[256];
  catv[t] = catc[b*256 + t];
  __syncthreads();
  float evl[4];
#pragma unroll
  for (int r2=0;r2<4;r2++){
    int l = t + r2*256;
    const u16x8* row = (const u16x8*)(y1 + ((long)l*64 + b)*256);
    float acc = 0.f;
    for (int f8=0; f8<32; f8++){
      u16x8 v = row[f8];
#pragma unroll
      for (int k=0;k<8;k++) acc += b2f(v[k]) * catv[f8*8+k];
    }
    ev[l] = acc; evl[r2] = acc;
  }
  float mx = fmaxf(fmaxf(evl[0],evl[1]), fmaxf(evl[2],evl[3]));
  red[t] = mx;
  __syncthreads();
  for (int s=128; s>0; s>>=1){ if (t < s) red[t] = fmaxf(red[t], red[t+s]); __syncthreads(); }
  float m = red[0];
  __syncthreads();
  float sum = 0.f;
#pragma unroll
  for (int r2=0;r2<4;r2++){
    int l = t + r2*256;
    float e = __expf(ev[l] - m);
    ev[l] = e; sum += e;
  }
  red[t] = sum;
  __syncthreads();
  for (int s=128; s>0; s>>=1){ if (t < s) red[t] += red[t+s]; __syncthreads(); }
  float rz = __builtin_amdgcn_rcpf(red[0]);
#pragma unroll
  for (int r2=0;r2<4;r2++){
    int l = t + r2*256;
    sT[(long)l*64 + b] = ev[l] * rz;
  }
#pragma unroll
  for (int r2=0;r2<4;r2++){
    int j = t + r2*256;
    const float* wr = (j < 512) ? (Wih2f + (long)j*512 + 256)
                                : (Wih2b + (long)(j-512)*512 + 256);
    const float4* w4 = (const float4*)wr;
    float acc = 0.f;
#pragma unroll 8
    for (int f4=0; f4<64; f4++){
      float4 v = w4[f4];
      acc += v.x*catv[f4*4+0] + v.y*catv[f4*4+1] + v.z*catv[f4*4+2] + v.w*catv[f4*4+3];
    }
    proj[b*1024 + j] = acc;
  }
}

// ---------------- feats = out2 @ Wout.T + bout ----------------
__global__ __launch_bounds__(256) void featk(const u16* __restrict__ y2,
    const float* __restrict__ Wout, const float* __restrict__ bout, float* __restrict__ feats)
{
  __shared__ float wlds[1280];
  int t = threadIdx.x;
  for (int k=t;k<1280;k+=256) wlds[k] = Wout[k];
  __syncthreads();
  long i = (long)blockIdx.x*256 + t;
  const u16x8* row = (const u16x8*)(y2 + i*256);
  float acc[5] = {0.f,0.f,0.f,0.f,0.f};
  for (int f8=0; f8<32; f8++){
    u16x8 v = row[f8];
#pragma unroll
    for (int k=0;k<8;k++){
      float x = b2f(v[k]);
      int f = f8*8 + k;
#pragma unroll
      for (int c=0;c<5;c++) acc[c] += x * wlds[c*256 + f];
    }
  }
#pragma unroll
  for (int c=0;c<5;c++) feats[i*5 + c] = acc[c] + bout[c];
}

// ---------------- CRF forward, exp domain: sc[c] = M + ln E[c] ----------------
__global__ void crf_kernel(const float* __restrict__ feats, const float* __restrict__ masks,
                           const float* __restrict__ trans, float* __restrict__ out)
{
  int b = threadIdx.x;  // 64
  float etr[5][5], tr4[5];
#pragma unroll
  for (int c=0;c<5;c++)
#pragma unroll
    for (int cp=0;cp<5;cp++) etr[c][cp] = __expf(trans[c*5+cp]);  // e^-10000 -> 0
#pragma unroll
  for (int cp=0;cp<5;cp++) tr4[cp] = trans[4*5+cp];   // STOP row
  float E[5] = {0.f, 0.f, 0.f, 1.f, 0.f};             // exp(sc), START=3
  float M = 0.f;
  const float* fpB = feats + (long)b*5120;
  float ftn[5], mtn;
#pragma unroll
  for (int c=0;c<5;c++) ftn[c] = fpB[c];
  mtn = masks[b*1024];
  for (int l=0;l<1024;l++){
    float ft[5]; float mt = mtn;
#pragma unroll
    for (int c=0;c<5;c++) ft[c] = ftn[c];
    if (l < 1023){
      const float* fp = fpB + (l + 1)*5;
#pragma unroll
      for (int c=0;c<5;c++) ftn[c] = fp[c];
      mtn = masks[b*1024 + l + 1];
    }
    float En[5];
#pragma unroll
    for (int c=0;c<5;c++){
      float S = E[0]*etr[c][0];
#pragma unroll
      for (int cp=1;cp<5;cp++) S = fmaf(E[cp], etr[c][cp], S);
      En[c] = S * __expf(ft[c]);
    }
    bool take = (mt > 0.5f);
#pragma unroll
    for (int c=0;c<5;c++) E[c] = take ? En[c] : E[c];
    // exact power-of-2 renorm
    float mx = fmaxf(fmaxf(fmaxf(E[0],E[1]), fmaxf(E[2],E[3])), E[4]);
    int k = (int)((__builtin_bit_cast(unsigned, mx) >> 23) & 0xFFu) - 127;
    float s = __builtin_bit_cast(float, (unsigned)(127 - k) << 23);
#pragma unroll
    for (int c=0;c<5;c++) E[c] *= s;
    M = fmaf((float)k, 0.6931471805599453f, M);
  }
  float Sf = 0.f;
#pragma unroll
  for (int cp=0;cp<5;cp++) Sf = fmaf(E[cp], __expf(tr4[cp]), Sf);
  out[b] = M + __logf(Sf);
}

// ---------------- launcher ----------------
extern "C" void kernel_launch(void* const* d_in, const int* in_sizes, int n_in,
                              void* d_out, int out_size, void* d_ws, size_t ws_size,
                              hipStream_t stream)
{
  const int*   sent  = (const int*)  d_in[0];
  const float* masks = (const float*)d_in[1];
  const float* emb   = (const float*)d_in[2];
  const float* Wih1f = (const float*)d_in[3];
  const float* Whh1f = (const float*)d_in[4];
  const float* bih1f = (const float*)d_in[5];
  const float* bhh1f = (const float*)d_in[6];
  const float* Wih1b = (const float*)d_in[7];
  const float* Whh1b = (const float*)d_in[8];
  const float* bih1b = (const float*)d_in[9];
  const float* bhh1b = (const float*)d_in[10];
  const float* Wih2f = (const float*)d_in[11];
  const float* Whh2f = (const float*)d_in[12];
  const float* bih2f = (const float*)d_in[13];
  const float* bhh2f = (const float*)d_in[14];
  const float* Wih2b = (const float*)d_in[15];
  const float* Whh2b = (const float*)d_in[16];
  const float* bih2b = (const float*)d_in[17];
  const float* bhh2b = (const float*)d_in[18];
  const float* Wout  = (const float*)d_in[19];
  const float* bout  = (const float*)d_in[20];
  const float* trans = (const float*)d_in[21];
  const float* h0    = (const float*)d_in[22];
  const float* c0    = (const float*)d_in[23];
  const float* h02   = (const float*)d_in[24];
  const float* c02   = (const float*)d_in[25];
  float* out = (float*)d_out;

  // workspace layout (aliased: X/y1/y2 share, G per layer shares). ~170.7 MB.
  char* ws = (char*)d_ws;
  u16*   Ybuf  = (u16*)(ws + 0);              // 33,554,432 B: X, then y1, then y2
  u16*   Gbuf  = (u16*)(ws + 33554432);       // 134,217,728 B: G'' per layer
  u16*   W1cat = (u16*)(ws + 167772160);      // 524,288 B
  u16*   WAcat = (u16*)(ws + 168296448);      // 524,288 B
  float* b1cat = (float*)(ws + 168820736);    // 4,096 B
  float* b2cat = (float*)(ws + 168824832);    // 4,096 B
  float* catcb = (float*)(ws + 168828928);    // 65,536 B
  float* sbuf  = (float*)(ws + 168894464);    // 262,144 B  (sT[l][64])
  float* projb = (float*)(ws + 169156608);    // 262,144 B
  float* featb = (float*)(ws + 169418752);    // 1,310,720 B

  conv_weights<<<1024, 256, 0, stream>>>(Wih1f, Wih1b, bih1f, bhh1f, bih1b, bhh1b,
                                         Wih2f, Wih2b, bih2f, bhh2f, bih2b, bhh2b,
                                         W1cat, WAcat, b1cat, b2cat);
  embed_gather<<<16384, 256, 0, stream>>>(sent, emb, Ybuf);
  gemm_bt<<<dim3(512, 8), 256, 0, stream>>>(Ybuf, W1cat, b1cat, Gbuf, 65536, 1024, 256);
  lstm_layer<<<8, 1024, 0, stream>>>(Gbuf, Whh1f, Whh1b, h0, c0, nullptr, nullptr, Ybuf, catcb);
  attn_kernel<<<64, 256, 0, stream>>>(Ybuf, catcb, Wih2f, Wih2b, sbuf, projb);
  gemm_bt<<<dim3(512, 8), 256, 0, stream>>>(Ybuf, WAcat, b2cat, Gbuf, 65536, 1024, 256);
  lstm_layer<<<8, 1024, 0, stream>>>(Gbuf, Whh2f, Whh2b, h02, c02, sbuf, projb, Ybuf, nullptr);
  featk<<<256, 256, 0, stream>>>(Ybuf, Wout, bout, featb);
  crf_kernel<<<1, 64, 0, stream>>>(featb, masks, trans, out);
}

// Round 6
// 2301.438 us; speedup vs baseline: 1.6666x; 1.1307x over previous
//
#include <hip/hip_runtime.h>
#include <hip/hip_bf16.h>

// BiLSTM-CRF forward. B=64, L=1024, E=256, H=128 (per dir), C=5, V=32000.
// R5: 16 persistent LSTM WGs (2 dirs x 8 batch-groups of 8). MFMA B-cols 8-15
// zero-padded; tau=1 cells redistributed to lanes lq>=8 via v_mov_dpp row_ror:8
// (VALU pipe, not LDS). Each thread owns exactly 1 cell -> per-CU VALU halves.
// G'' layout [grp16][l][tid][4]: one dwordx2 gate load per thread/step.

typedef unsigned short u16;
typedef unsigned int u32;
typedef __bf16 v8bf __attribute__((ext_vector_type(8)));
typedef float  v4f  __attribute__((ext_vector_type(4)));
typedef unsigned short u16x8 __attribute__((ext_vector_type(8)));
typedef unsigned short u16x4 __attribute__((ext_vector_type(4)));

__device__ __forceinline__ float b2f(u16 b){
  return __builtin_bit_cast(float, ((unsigned)b) << 16);
}
__device__ __forceinline__ u16 f2b(float x){           // RNE f32->bf16
  unsigned u = __builtin_bit_cast(unsigned, x);
  unsigned r = (u + 0x7FFFu + ((u >> 16) & 1u)) >> 16;
  return (u16)r;
}
__device__ __forceinline__ float xor8(float x){        // lane <- lane^8 (row_ror:8)
  int t = __builtin_amdgcn_mov_dpp(__builtin_bit_cast(int, x), 0x128, 0xF, 0xF, true);
  return __builtin_bit_cast(float, t);
}

// ---------------- weight prep: concat + fp32->bf16 ----------------
__global__ __launch_bounds__(256) void conv_weights(
    const float* __restrict__ Wih1f, const float* __restrict__ Wih1b,
    const float* __restrict__ bih1f, const float* __restrict__ bhh1f,
    const float* __restrict__ bih1b, const float* __restrict__ bhh1b,
    const float* __restrict__ Wih2f, const float* __restrict__ Wih2b,
    const float* __restrict__ bih2f, const float* __restrict__ bhh2f,
    const float* __restrict__ bih2b, const float* __restrict__ bhh2b,
    u16* __restrict__ W1cat, u16* __restrict__ WAcat,
    float* __restrict__ b1cat, float* __restrict__ b2cat)
{
  int gid = blockIdx.x * 256 + threadIdx.x;   // 1024*256 = 262144
  int j = gid >> 8, e = gid & 255;
  float w1 = (j < 512) ? Wih1f[j*256 + e] : Wih1b[(j-512)*256 + e];
  float wa = (j < 512) ? Wih2f[j*512 + e] : Wih2b[(j-512)*512 + e];  // cols 0..255
  W1cat[gid] = f2b(w1);
  WAcat[gid] = f2b(wa);
  if (e == 0){
    b1cat[j] = (j < 512) ? (bih1f[j] + bhh1f[j]) : (bih1b[j-512] + bhh1b[j-512]);
    b2cat[j] = (j < 512) ? (bih2f[j] + bhh2f[j]) : (bih2b[j-512] + bhh2b[j-512]);
  }
}

// ---------------- embedding gather (flat order == reshape(L,B,E)) ----------------
__global__ __launch_bounds__(256) void embed_gather(
    const int* __restrict__ sent, const float* __restrict__ emb, u16* __restrict__ X)
{
  int w = threadIdx.x >> 6, lane = threadIdx.x & 63;
  long i = (long)blockIdx.x * 4 + w;          // row of X, 0..65535
  int idx = sent[i];
  const float4* src = (const float4*)(emb + (long)idx * 256);
  float4 v = src[lane];
  u16x4 o; o[0] = f2b(v.x); o[1] = f2b(v.y); o[2] = f2b(v.z); o[3] = f2b(v.w);
  *(u16x4*)(X + i*256 + lane*4) = o;
}

// ---- bf16 MFMA GEMM, A[MxK] rm, B[NxK] rm, +bias; writes G''[grp][l][thr][4] ----
// element (i,j): l=i>>6, b=i&63; dirj=j>>9, g=(j>>7)&3 (gate), u=j&127 (unit)
// v=u>>3, qd=(u>>1)&3, tb=u&1; grp=dirj*8+(b>>3); thr=v*64+qd*16+tb*8+(b&7); z=g
__global__ __launch_bounds__(256) void gemm_bt(
    const u16* __restrict__ A, const u16* __restrict__ Bm,
    const float* __restrict__ bias, u16* __restrict__ Gp,
    int M, int N, int K)
{
  __shared__ __align__(16) u16 As[128*64];
  __shared__ __align__(16) u16 Bs[128*64];
  int tid = threadIdx.x;
  int w = tid >> 6, lane = tid & 63;
  int lq = lane & 15, quad = lane >> 4;
  int wm = w & 1, wn = w >> 1;
  long m0 = (long)blockIdx.x * 128;
  int n0 = blockIdx.y * 128;
  v4f acc[4][4];
  v4f zero = {0.f, 0.f, 0.f, 0.f};
#pragma unroll
  for (int i=0;i<4;i++)
#pragma unroll
    for (int j=0;j<4;j++) acc[i][j] = zero;

  for (int k0 = 0; k0 < K; k0 += 64){
#pragma unroll
    for (int c = 0; c < 4; c++){
      int lin = c*256 + tid;
      int row = lin >> 3, chunk = lin & 7;            // 128 rows x 8 chunks(16B)
      u16x8 av = *(const u16x8*)(A + (m0+row)*K + k0 + chunk*8);
      u16x8 bv = *(const u16x8*)(Bm + ((long)(n0+row))*K + k0 + chunk*8);
      int sw = chunk ^ (row & 7);                     // XOR swizzle vs bank conflicts
      *(u16x8*)(As + row*64 + sw*8) = av;
      *(u16x8*)(Bs + row*64 + sw*8) = bv;
    }
    __syncthreads();
#pragma unroll
    for (int s = 0; s < 2; s++){
      v8bf af[4], bf_[4];
#pragma unroll
      for (int i=0;i<4;i++){
        int row = wm*64 + i*16 + lq;
        int ch  = (s*4 + quad) ^ (row & 7);
        af[i] = __builtin_bit_cast(v8bf, *(const u16x8*)(As + row*64 + ch*8));
      }
#pragma unroll
      for (int j=0;j<4;j++){
        int row = wn*64 + j*16 + lq;
        int ch  = (s*4 + quad) ^ (row & 7);
        bf_[j] = __builtin_bit_cast(v8bf, *(const u16x8*)(Bs + row*64 + ch*8));
      }
#pragma unroll
      for (int i=0;i<4;i++)
#pragma unroll
        for (int j=0;j<4;j++)
          acc[i][j] = __builtin_amdgcn_mfma_f32_16x16x32_bf16(af[i], bf_[j], acc[i][j], 0, 0, 0);
    }
    __syncthreads();
  }
#pragma unroll
  for (int jt=0;jt<4;jt++){
    int j = n0 + wn*64 + jt*16 + lq;
    float bv = bias[j];
    int dirj = j >> 9, g = (j >> 7) & 3, u = j & 127;
    int v_ = u >> 3, qd = (u >> 1) & 3, tb = u & 1;
    int tidl = v_*64 + qd*16 + tb*8;
#pragma unroll
    for (int i16=0;i16<4;i16++){
#pragma unroll
      for (int r2=0;r2<4;r2++){
        long i = m0 + wm*64 + i16*16 + quad*4 + r2;
        int bb = (int)(i & 63); long l = i >> 6;
        long off = ((long)(dirj*8 + (bb>>3)) << 22) + (l << 12)
                 + (long)(tidl + (bb&7))*4 + g;
        Gp[off] = f2b(acc[i16][jt][r2] + bv);
      }
    }
  }
}

// ---------------- persistent BiLSTM layer: 16 WGs x 1024 thr (2 dirs x 8 bgroups) ----
// Thread (v=tid>>6, quad, lq): owns ONE cell: batch=b0+(lq&7), unit U=v*8+2q+(lq>>3).
// MFMA tiles: A rows m = gate(m&3) of unit v*8+tau+2*(m>>2); B cols = 8 batches + 8 zero.
// acc[1] (tau=1 cells) redistributed to lanes lq>=8 via DPP row_ror:8.
// G'': [grp][l][tid][4] bf16 (grp = dir*8+bg). Y: [l*64+b][256] bf16 (dir at col d*128).
__global__ __launch_bounds__(1024, 4) void lstm_layer(
    const u16* __restrict__ G, const float* __restrict__ WhhF, const float* __restrict__ WhhB,
    const float* __restrict__ h0, const float* __restrict__ c0,
    const float* __restrict__ sT, const float* __restrict__ proj,
    u16* __restrict__ Y, float* __restrict__ catOut)
{
  int blk = blockIdx.x;
  int dir = blk >> 3, bg = blk & 7, b0 = bg * 8;
  int tid = threadIdx.x, v = tid >> 6, lane = tid & 63;
  int quad = lane >> 4, lq = lane & 15;
  int b7 = lq & 7, tb = lq >> 3;
  int U = v*8 + 2*quad + tb;                  // this thread's hidden unit
  int batch = b0 + b7;
  const float* Whh = dir ? WhhB : WhhF;

  __shared__ __align__(16) u16 hbuf[2][2048]; // h[16 rows][128], rows 8-15 = zeros

  // A-frags in registers: lane holds A[m=lq][k=ks*32+quad*8+j]
  // tile tau row m: gate = m&3, unit = v*8 + tau + 2*(m>>2)
  v8bf Af[2][4];
  {
    int gate = lq & 3;
#pragma unroll
    for (int tau=0;tau<2;tau++){
      int unit = v*8 + tau + 2*(lq>>2);
      const float* wr = Whh + (long)(gate*128 + unit)*128;
#pragma unroll
      for (int ks=0;ks<4;ks++){
        u16x8 tmp;
#pragma unroll
        for (int jj=0;jj<8;jj++) tmp[jj] = f2b(wr[ks*32 + quad*8 + jj]);
        Af[tau][ks] = __builtin_bit_cast(v8bf, tmp);
      }
    }
  }

  // zero pad rows 8-15 (both buffers); write own h0 cell (swizzled chunk = U>>3 = v)
  hbuf[0][1024 + tid] = 0;
  hbuf[1][1024 + tid] = 0;
  int wOff = b7*128 + ((v ^ b7) * 8) + 2*quad + tb;
  int rOff[4];
#pragma unroll
  for (int ks=0;ks<4;ks++) rOff[ks] = lq*128 + (((ks*4 + quad) ^ lq) * 8);

  float cc = c0[dir*8192 + batch*128 + U];
  hbuf[0][wOff] = f2b(h0[dir*8192 + batch*128 + U]);

  // attention fold (LSTM2): pr[g] = 64*proj[batch, dir*512 + g*128 + U]
  bool att = (proj != nullptr);
  float pr[4];
  if (att){
#pragma unroll
    for (int g=0;g<4;g++)
      pr[g] = 64.0f * proj[(long)batch*1024 + dir*512 + g*128 + U];
  }

  const u16x4* Gp = (const u16x4*)(G + ((size_t)blk << 22)) + tid;
  long dl = dir ? -1 : 1;
  long l0 = dir ? 1023 : 0;
  u16x4 gbuf[2];
  gbuf[0] = Gp[l0 << 10];
  gbuf[1] = Gp[(l0 + dl) << 10];
  const u16x4* gpf = Gp + ((l0 + 2*dl) << 10);  // runs 2 past end: ws-internal, harmless
  u16* yp = Y + (l0*64 + batch)*256 + dir*128 + U;
  const float* sp = att ? (sT + l0*64 + batch) : nullptr;
  bool low = (tb == 0);
  __syncthreads();

  const float NL2E = -1.4426950408889634f;
  const float N2L2E = -2.8853900817779268f;
  v4f zero4 = {0.f, 0.f, 0.f, 0.f};

#pragma unroll 2
  for (int it = 0; it < 1024; ++it){
    int slot = it & 1;
    float gc[4];
#pragma unroll
    for (int z=0; z<4; z++) gc[z] = b2f(gbuf[slot][z]);
    gbuf[slot] = *gpf;                 // prefetch it+2 (same parity slot)
    gpf += dl << 10;
    // h fragments from LDS (B operand, cols 8-15 zero)
    v8bf bh[4];
#pragma unroll
    for (int ks=0;ks<4;ks++)
      bh[ks] = __builtin_bit_cast(v8bf, *(const u16x8*)(&hbuf[slot][rOff[ks]]));
    v4f acc[2];
    acc[0] = zero4; acc[1] = zero4;
#pragma unroll
    for (int ks=0;ks<4;ks++)
#pragma unroll
      for (int tau=0;tau<2;tau++)
        acc[tau] = __builtin_amdgcn_mfma_f32_16x16x32_bf16(Af[tau][ks], bh[ks], acc[tau], 0, 0, 0);

    // redistribute: lanes lq<8 keep acc[0] (own col); lanes lq>=8 take acc[1]
    // from lane-8 (their cell's col lives there). Then add gates (+attention).
    float val[4];
#pragma unroll
    for (int r=0;r<4;r++){
      float t = xor8(acc[1][r]);
      val[r] = (low ? acc[0][r] : t) + gc[r];
    }
    if (att){
      float s = *sp;
      sp += dl*64;
#pragma unroll
      for (int r=0;r<4;r++) val[r] = fmaf(s, pr[r], val[r]);
    }

    float i_ = val[0], f_ = val[1], g_ = val[2], o_ = val[3];
    float ef = __builtin_amdgcn_exp2f(f_ * NL2E);
    float ei = __builtin_amdgcn_exp2f(i_ * NL2E);
    float eg = __builtin_amdgcn_exp2f(fminf(g_ * N2L2E, 115.0f));
    float sf = __builtin_amdgcn_rcpf(1.0f + ef);
    float p  = (1.0f - eg) * __builtin_amdgcn_rcpf((1.0f + ei) * (1.0f + eg));
    float c2 = fmaf(cc, sf, p);
    cc = c2;
    float eo = __builtin_amdgcn_exp2f(o_ * NL2E);
    float ec = __builtin_amdgcn_exp2f(fminf(c2 * N2L2E, 115.0f));
    float hv = (1.0f - ec) * __builtin_amdgcn_rcpf((1.0f + eo) * (1.0f + ec));

    u16 hb = f2b(hv);
    hbuf[slot^1][wOff] = hb;
    *yp = hb;
    yp += dl*16384;
    __syncthreads();
  }
  if (catOut)
    catOut[(long)batch*256 + dir*128 + U] = cc;
}

// ---------------- attention: e = fbout . catc, softmax over L, proj = catc @ Wih2[:,256:].T ----
// s written TRANSPOSED: sT[l*64 + b]
__global__ __launch_bounds__(256) void attn_kernel(
    const u16* __restrict__ y1, const float* __restrict__ catc,
    const float* __restrict__ Wih2f, const float* __restrict__ Wih2b,
    float* __restrict__ sT, float* __restrict__ proj)
{
  int b = blockIdx.x, t = threadIdx.x;
  __shared__ float catv[256];
  __shared__ float ev[1024];
  __shared__ float red[256];
  catv[t] = catc[b*256 + t];
  __syncthreads();
  float evl[4];
#pragma unroll
  for (int r2=0;r2<4;r2++){
    int l = t + r2*256;
    const u16x8* row = (const u16x8*)(y1 + ((long)l*64 + b)*256);
    float acc = 0.f;
    for (int f8=0; f8<32; f8++){
      u16x8 v = row[f8];
#pragma unroll
      for (int k=0;k<8;k++) acc += b2f(v[k]) * catv[f8*8+k];
    }
    ev[l] = acc; evl[r2] = acc;
  }
  float mx = fmaxf(fmaxf(evl[0],evl[1]), fmaxf(evl[2],evl[3]));
  red[t] = mx;
  __syncthreads();
  for (int s=128; s>0; s>>=1){ if (t < s) red[t] = fmaxf(red[t], red[t+s]); __syncthreads(); }
  float m = red[0];
  __syncthreads();
  float sum = 0.f;
#pragma unroll
  for (int r2=0;r2<4;r2++){
    int l = t + r2*256;
    float e = __expf(ev[l] - m);
    ev[l] = e; sum += e;
  }
  red[t] = sum;
  __syncthreads();
  for (int s=128; s>0; s>>=1){ if (t < s) red[t] += red[t+s]; __syncthreads(); }
  float rz = __builtin_amdgcn_rcpf(red[0]);
#pragma unroll
  for (int r2=0;r2<4;r2++){
    int l = t + r2*256;
    sT[(long)l*64 + b] = ev[l] * rz;
  }
#pragma unroll
  for (int r2=0;r2<4;r2++){
    int j = t + r2*256;
    const float* wr = (j < 512) ? (Wih2f + (long)j*512 + 256)
                                : (Wih2b + (long)(j-512)*512 + 256);
    const float4* w4 = (const float4*)wr;
    float acc = 0.f;
#pragma unroll 8
    for (int f4=0; f4<64; f4++){
      float4 v = w4[f4];
      acc += v.x*catv[f4*4+0] + v.y*catv[f4*4+1] + v.z*catv[f4*4+2] + v.w*catv[f4*4+3];
    }
    proj[b*1024 + j] = acc;
  }
}

// ---------------- feats = out2 @ Wout.T + bout ----------------
__global__ __launch_bounds__(256) void featk(const u16* __restrict__ y2,
    const float* __restrict__ Wout, const float* __restrict__ bout, float* __restrict__ feats)
{
  __shared__ float wlds[1280];
  int t = threadIdx.x;
  for (int k=t;k<1280;k+=256) wlds[k] = Wout[k];
  __syncthreads();
  long i = (long)blockIdx.x*256 + t;
  const u16x8* row = (const u16x8*)(y2 + i*256);
  float acc[5] = {0.f,0.f,0.f,0.f,0.f};
  for (int f8=0; f8<32; f8++){
    u16x8 v = row[f8];
#pragma unroll
    for (int k=0;k<8;k++){
      float x = b2f(v[k]);
      int f = f8*8 + k;
#pragma unroll
      for (int c=0;c<5;c++) acc[c] += x * wlds[c*256 + f];
    }
  }
#pragma unroll
  for (int c=0;c<5;c++) feats[i*5 + c] = acc[c] + bout[c];
}

// ---------------- CRF forward, exp domain: sc[c] = M + ln E[c] ----------------
__global__ void crf_kernel(const float* __restrict__ feats, const float* __restrict__ masks,
                           const float* __restrict__ trans, float* __restrict__ out)
{
  int b = threadIdx.x;  // 64
  float etr[5][5], tr4[5];
#pragma unroll
  for (int c=0;c<5;c++)
#pragma unroll
    for (int cp=0;cp<5;cp++) etr[c][cp] = __expf(trans[c*5+cp]);  // e^-10000 -> 0
#pragma unroll
  for (int cp=0;cp<5;cp++) tr4[cp] = trans[4*5+cp];   // STOP row
  float E[5] = {0.f, 0.f, 0.f, 1.f, 0.f};             // exp(sc), START=3
  float M = 0.f;
  const float* fpB = feats + (long)b*5120;
  float ftn[5], mtn;
#pragma unroll
  for (int c=0;c<5;c++) ftn[c] = fpB[c];
  mtn = masks[b*1024];
  for (int l=0;l<1024;l++){
    float ft[5]; float mt = mtn;
#pragma unroll
    for (int c=0;c<5;c++) ft[c] = ftn[c];
    if (l < 1023){
      const float* fp = fpB + (l + 1)*5;
#pragma unroll
      for (int c=0;c<5;c++) ftn[c] = fp[c];
      mtn = masks[b*1024 + l + 1];
    }
    float En[5];
#pragma unroll
    for (int c=0;c<5;c++){
      float S = E[0]*etr[c][0];
#pragma unroll
      for (int cp=1;cp<5;cp++) S = fmaf(E[cp], etr[c][cp], S);
      En[c] = S * __expf(ft[c]);
    }
    bool take = (mt > 0.5f);
#pragma unroll
    for (int c=0;c<5;c++) E[c] = take ? En[c] : E[c];
    // exact power-of-2 renorm
    float mx = fmaxf(fmaxf(fmaxf(E[0],E[1]), fmaxf(E[2],E[3])), E[4]);
    int k = (int)((__builtin_bit_cast(unsigned, mx) >> 23) & 0xFFu) - 127;
    float s = __builtin_bit_cast(float, (unsigned)(127 - k) << 23);
#pragma unroll
    for (int c=0;c<5;c++) E[c] *= s;
    M = fmaf((float)k, 0.6931471805599453f, M);
  }
  float Sf = 0.f;
#pragma unroll
  for (int cp=0;cp<5;cp++) Sf = fmaf(E[cp], __expf(tr4[cp]), Sf);
  out[b] = M + __logf(Sf);
}

// ---------------- launcher ----------------
extern "C" void kernel_launch(void* const* d_in, const int* in_sizes, int n_in,
                              void* d_out, int out_size, void* d_ws, size_t ws_size,
                              hipStream_t stream)
{
  const int*   sent  = (const int*)  d_in[0];
  const float* masks = (const float*)d_in[1];
  const float* emb   = (const float*)d_in[2];
  const float* Wih1f = (const float*)d_in[3];
  const float* Whh1f = (const float*)d_in[4];
  const float* bih1f = (const float*)d_in[5];
  const float* bhh1f = (const float*)d_in[6];
  const float* Wih1b = (const float*)d_in[7];
  const float* Whh1b = (const float*)d_in[8];
  const float* bih1b = (const float*)d_in[9];
  const float* bhh1b = (const float*)d_in[10];
  const float* Wih2f = (const float*)d_in[11];
  const float* Whh2f = (const float*)d_in[12];
  const float* bih2f = (const float*)d_in[13];
  const float* bhh2f = (const float*)d_in[14];
  const float* Wih2b = (const float*)d_in[15];
  const float* Whh2b = (const float*)d_in[16];
  const float* bih2b = (const float*)d_in[17];
  const float* bhh2b = (const float*)d_in[18];
  const float* Wout  = (const float*)d_in[19];
  const float* bout  = (const float*)d_in[20];
  const float* trans = (const float*)d_in[21];
  const float* h0    = (const float*)d_in[22];
  const float* c0    = (const float*)d_in[23];
  const float* h02   = (const float*)d_in[24];
  const float* c02   = (const float*)d_in[25];
  float* out = (float*)d_out;

  // workspace layout (aliased: X/y1/y2 share, G per layer shares). ~170.7 MB.
  char* ws = (char*)d_ws;
  u16*   Ybuf  = (u16*)(ws + 0);              // 33,554,432 B: X, then y1, then y2
  u16*   Gbuf  = (u16*)(ws + 33554432);       // 134,217,728 B: G'' per layer
  u16*   W1cat = (u16*)(ws + 167772160);      // 524,288 B
  u16*   WAcat = (u16*)(ws + 168296448);      // 524,288 B
  float* b1cat = (float*)(ws + 168820736);    // 4,096 B
  float* b2cat = (float*)(ws + 168824832);    // 4,096 B
  float* catcb = (float*)(ws + 168828928);    // 65,536 B
  float* sbuf  = (float*)(ws + 168894464);    // 262,144 B  (sT[l][64])
  float* projb = (float*)(ws + 169156608);    // 262,144 B
  float* featb = (float*)(ws + 169418752);    // 1,310,720 B

  conv_weights<<<1024, 256, 0, stream>>>(Wih1f, Wih1b, bih1f, bhh1f, bih1b, bhh1b,
                                         Wih2f, Wih2b, bih2f, bhh2f, bih2b, bhh2b,
                                         W1cat, WAcat, b1cat, b2cat);
  embed_gather<<<16384, 256, 0, stream>>>(sent, emb, Ybuf);
  gemm_bt<<<dim3(512, 8), 256, 0, stream>>>(Ybuf, W1cat, b1cat, Gbuf, 65536, 1024, 256);
  lstm_layer<<<16, 1024, 0, stream>>>(Gbuf, Whh1f, Whh1b, h0, c0, nullptr, nullptr, Ybuf, catcb);
  attn_kernel<<<64, 256, 0, stream>>>(Ybuf, catcb, Wih2f, Wih2b, sbuf, projb);
  gemm_bt<<<dim3(512, 8), 256, 0, stream>>>(Ybuf, WAcat, b2cat, Gbuf, 65536, 1024, 256);
  lstm_layer<<<16, 1024, 0, stream>>>(Gbuf, Whh2f, Whh2b, h02, c02, sbuf, projb, Ybuf, nullptr);
  featk<<<256, 256, 0, stream>>>(Ybuf, Wout, bout, featb);
  crf_kernel<<<1, 64, 0, stream>>>(featb, masks, trans, out);
}